// Round 2
// baseline (529.657 us; speedup 1.0000x reference)
//
#include <hip/hip_runtime.h>
#include <math.h>

#define Bn 64
#define QLn 40
#define ALn 60
#define Dn 300
#define Cn 256
#define Kn 3
#define Hn 256
#define HLUn 512
#define AHn 256
#define W3 768   /* Kn*Cn */

// ---------------- gather embeddings + row norms ----------------
__global__ void k_gather(const int* __restrict__ q, const int* __restrict__ a,
                         const float* __restrict__ emb,
                         float* __restrict__ s1, float* __restrict__ s2,
                         float* __restrict__ nq, float* __restrict__ na) {
  int row = blockIdx.x;
  const int* idxp; float* dst; float* nrm; int r;
  if (row < Bn*QLn) { idxp = q; dst = s1; nrm = nq; r = row; }
  else              { idxp = a; dst = s2; nrm = na; r = row - Bn*QLn; }
  int tok = idxp[r];
  const float* src = emb + (size_t)tok * Dn;
  float* d = dst + (size_t)r * Dn;
  float ssq = 0.f;
  for (int i = threadIdx.x; i < Dn; i += 64) {
    float v = src[i]; d[i] = v; ssq += v * v;
  }
  #pragma unroll
  for (int off = 32; off; off >>= 1) ssq += __shfl_down(ssq, off, 64);
  if (threadIdx.x == 0) nrm[r] = sqrtf(ssq);
}

// ---------------- repack conv weight (K,D,C) -> (D, K*C) ----------------
__global__ void k_repack(const float* __restrict__ w, float* __restrict__ wf) {
  int i = blockIdx.x * 256 + threadIdx.x;
  if (i >= Kn * Dn * Cn) return;
  int k = i / (Dn * Cn);
  int rem = i % (Dn * Cn);
  int d = rem / Cn, c = rem % Cn;
  wf[(size_t)d * W3 + k * Cn + c] = w[i];
}

// ---------------- generic fp32 GEMM: C = act(A@B + bias) ----------------
// A [M,K] lda, B [K,N] ldb (row major), C [M,N] ldc. act: 0=none, 1=tanh
__global__ __launch_bounds__(256) void k_gemm(
    const float* __restrict__ A, const float* __restrict__ Bm, float* __restrict__ C,
    int M, int N, int Kd, int lda, int ldb, int ldc,
    const float* __restrict__ bias, int act) {
  __shared__ __align__(16) float As[16][68];
  __shared__ __align__(16) float Bs[16][64];
  int tid = threadIdx.x;
  int tx = tid & 15, ty = tid >> 4;
  int rowBase = blockIdx.x * 64;
  int colBase = blockIdx.y * 64;
  float acc[4][4] = {{0.f}};
  for (int k0 = 0; k0 < Kd; k0 += 16) {
    #pragma unroll
    for (int j = 0; j < 4; ++j) {
      int idx = tid + j * 256;
      int m = idx >> 4, kk = idx & 15;
      int gr = rowBase + m, gk = k0 + kk;
      As[kk][m] = (gr < M && gk < Kd) ? A[(size_t)gr * lda + gk] : 0.f;
    }
    #pragma unroll
    for (int j = 0; j < 4; ++j) {
      int idx = tid + j * 256;
      int kk = idx >> 6, n = idx & 63;
      int gk = k0 + kk, gc = colBase + n;
      Bs[kk][n] = (gk < Kd && gc < N) ? Bm[(size_t)gk * ldb + gc] : 0.f;
    }
    __syncthreads();
    #pragma unroll
    for (int kk = 0; kk < 16; ++kk) {
      float4 av = *reinterpret_cast<const float4*>(&As[kk][ty << 2]);
      float4 bv = *reinterpret_cast<const float4*>(&Bs[kk][tx << 2]);
      float ar[4] = {av.x, av.y, av.z, av.w};
      float br[4] = {bv.x, bv.y, bv.z, bv.w};
      #pragma unroll
      for (int i = 0; i < 4; ++i)
        #pragma unroll
        for (int jj = 0; jj < 4; ++jj)
          acc[i][jj] = fmaf(ar[i], br[jj], acc[i][jj]);
    }
    __syncthreads();
  }
  #pragma unroll
  for (int i = 0; i < 4; ++i) {
    int row = rowBase + (ty << 2) + i;
    if (row >= M) continue;
    #pragma unroll
    for (int jj = 0; jj < 4; ++jj) {
      int col = colBase + (tx << 2) + jj;
      if (col >= N) continue;
      float v = acc[i][jj];
      if (bias) v += bias[col];
      if (act == 1) v = tanhf(v);
      C[(size_t)row * ldc + col] = v;
    }
  }
}

// ---------------- sm conv combine + relu + maxpool over time ----------------
// Z row r = n*L + t, cols k*256+c. pooled[n,c] = max_t relu(b + sum_k Z[n*L+t+k, k*256+c])
__global__ void k_pool_sm(const float* __restrict__ Z1, const float* __restrict__ Z2,
                          const float* __restrict__ convb, float* __restrict__ pooled) {
  int blk = blockIdx.x;  // 0..63 question, 64..127 answer
  int c = threadIdx.x;
  const float* Z; int n, L;
  if (blk < Bn) { Z = Z1; n = blk; L = QLn; }
  else          { Z = Z2; n = blk - Bn; L = ALn; }
  float bias = convb[c];
  const float* base = Z + (size_t)n * L * W3;
  float m = 0.f;
  for (int t = 0; t <= L - 3; ++t) {
    float v = bias + base[t * W3 + c] + base[(t + 1) * W3 + 256 + c]
                   + base[(t + 2) * W3 + 512 + c];
    m = fmaxf(m, v);   // relu folded: m starts at 0
  }
  pooled[(size_t)blk * 256 + c] = m;
}

// ---------------- cosine similarity matrix ----------------
__global__ void k_cos(const float* __restrict__ s1, const float* __restrict__ s2,
                      const float* __restrict__ nq, const float* __restrict__ na,
                      float* __restrict__ cosb) {
  int bq = blockIdx.x;           // b*QLn + q
  int b = bq / QLn;
  __shared__ float s1row[Dn];
  for (int i = threadIdx.x; i < Dn; i += 64)
    s1row[i] = s1[(size_t)bq * Dn + i];
  __syncthreads();
  int a = threadIdx.x;
  if (a < ALn) {
    const float4* s2v = reinterpret_cast<const float4*>(s2 + ((size_t)b * ALn + a) * Dn);
    float dot = 0.f;
    #pragma unroll 5
    for (int d4 = 0; d4 < Dn / 4; ++d4) {
      float4 v = s2v[d4];
      dot += s1row[d4*4+0]*v.x + s1row[d4*4+1]*v.y + s1row[d4*4+2]*v.z + s1row[d4*4+3]*v.w;
    }
    float den = fmaxf(nq[bq] * na[b * ALn + a], 1e-6f);
    cosb[(size_t)bq * ALn + a] = dot / den;
  }
}

// ---------------- ctx conv via cos * S2W, relu + maxpool ----------------
__global__ void k_ctx(const float* __restrict__ S2W, const float* __restrict__ cosb,
                      const float* __restrict__ ctxb, float* __restrict__ pooled_ctx) {
  int bq = blockIdx.x;
  int b = bq / QLn;
  int c = threadIdx.x;
  __shared__ float cl[ALn];
  if (threadIdx.x < ALn) cl[threadIdx.x] = cosb[(size_t)bq * ALn + threadIdx.x];
  __syncthreads();
  const float* base = S2W + (size_t)b * ALn * W3;
  float bias = ctxb[c];
  float m = 0.f;
  for (int t = 0; t <= ALn - 3; ++t) {
    float v = bias + cl[t]     * base[t * W3 + c]
                   + cl[t + 1] * base[(t + 1) * W3 + 256 + c]
                   + cl[t + 2] * base[(t + 2) * W3 + 512 + c];
    m = fmaxf(m, v);
  }
  pooled_ctx[(size_t)bq * 256 + c] = m;
}

// ---------------- copy sent1 into qa_comb cols 256..555 ----------------
__global__ void k_copy_s1(const float* __restrict__ s1, float* __restrict__ qa) {
  int i = blockIdx.x * 256 + threadIdx.x;
  if (i >= Bn * QLn * Dn) return;
  int r = i / Dn, j = i % Dn;
  qa[(size_t)r * 556 + 256 + j] = s1[i];
}

// ---------------- score = hidden @ probW ----------------
__global__ void k_score(const float* __restrict__ hidden, const float* __restrict__ probW,
                        float* __restrict__ score) {
  int r = blockIdx.x;
  float v = hidden[(size_t)r * 256 + threadIdx.x] * probW[threadIdx.x];
  #pragma unroll
  for (int off = 32; off; off >>= 1) v += __shfl_down(v, off, 64);
  __shared__ float wsum[4];
  if ((threadIdx.x & 63) == 0) wsum[threadIdx.x >> 6] = v;
  __syncthreads();
  if (threadIdx.x == 0) score[r] = wsum[0] + wsum[1] + wsum[2] + wsum[3];
}

// ---------------- softmax over q + weighted feat pool -> feature3 ----------------
__global__ void k_attnpool(const float* __restrict__ score, const float* __restrict__ qa,
                           float* __restrict__ feat_comb) {
  int b = blockIdx.x;
  __shared__ float p[QLn];
  __shared__ float inv;
  if (threadIdx.x == 0) {
    float mx = -1e30f;
    for (int qq = 0; qq < QLn; ++qq) mx = fmaxf(mx, score[b * QLn + qq]);
    float den = 0.f;
    for (int qq = 0; qq < QLn; ++qq) {
      float e = expf(score[b * QLn + qq] - mx);
      p[qq] = e; den += e;
    }
    inv = 1.f / den;
  }
  __syncthreads();
  int c = threadIdx.x;
  float acc = 0.f;
  for (int qq = 0; qq < QLn; ++qq)
    acc += p[qq] * qa[((size_t)b * QLn + qq) * 556 + c];
  feat_comb[(size_t)b * 768 + 512 + c] = acc * inv;
}

// ---------------- concat feature1|feature2 into feat_comb cols 0..511 ----------------
__global__ void k_concat12(const float* __restrict__ features, float* __restrict__ feat_comb) {
  int i = blockIdx.x * 256 + threadIdx.x;
  if (i >= Bn * 512) return;
  int n = i >> 9, j = i & 511;
  float v = (j < 256) ? features[n * 256 + j] : features[(Bn + n) * 256 + (j - 256)];
  feat_comb[(size_t)n * 768 + j] = v;
}

// ---------------- batchnorm (training stats) + tanh ----------------
__global__ void k_bn_tanh(const float* __restrict__ h, const float* __restrict__ gamma,
                          const float* __restrict__ beta, float* __restrict__ outp) {
  int j = blockIdx.x;       // column 0..511
  int n = threadIdx.x;      // row 0..63, one wave
  float v = h[(size_t)n * HLUn + j];
  float s = v;
  #pragma unroll
  for (int off = 32; off; off >>= 1) s += __shfl_down(s, off, 64);
  float mu = __shfl(s, 0, 64) * (1.f / 64.f);
  float d = v - mu;
  float s2 = d * d;
  #pragma unroll
  for (int off = 32; off; off >>= 1) s2 += __shfl_down(s2, off, 64);
  float var = __shfl(s2, 0, 64) * (1.f / 64.f);
  float y = d * rsqrtf(var + 1e-5f) * gamma[j] + beta[j];
  outp[(size_t)n * HLUn + j] = tanhf(y);
}

// ---------------- head: logits + log_softmax (2 classes) ----------------
__global__ void k_head(const float* __restrict__ feat_out, const float* __restrict__ W2,
                       const float* __restrict__ b2, float* __restrict__ preds) {
  int n = blockIdx.x;
  int tid = threadIdx.x;
  float a0 = 0.f, a1 = 0.f;
  for (int j = tid; j < HLUn; j += 64) {
    float f = feat_out[(size_t)n * HLUn + j];
    a0 += f * W2[j * 2 + 0];
    a1 += f * W2[j * 2 + 1];
  }
  #pragma unroll
  for (int off = 32; off; off >>= 1) {
    a0 += __shfl_down(a0, off, 64);
    a1 += __shfl_down(a1, off, 64);
  }
  if (tid == 0) {
    float l0 = a0 + b2[0], l1 = a1 + b2[1];
    float mx = fmaxf(l0, l1);
    float lse = mx + logf(expf(l0 - mx) + expf(l1 - mx));
    preds[n * 2 + 0] = l0 - lse;
    preds[n * 2 + 1] = l1 - lse;
  }
}

extern "C" void kernel_launch(void* const* d_in, const int* in_sizes, int n_in,
                              void* d_out, int out_size, void* d_ws, size_t ws_size,
                              hipStream_t stream) {
  (void)in_sizes; (void)n_in; (void)out_size; (void)ws_size;
  const int*   question  = (const int*)d_in[0];
  const int*   answer    = (const int*)d_in[1];
  // d_in[2] = ext_feats: unused by the reference math
  const float* embedding = (const float*)d_in[3];
  const float* sm_convW  = (const float*)d_in[4];
  const float* sm_convb  = (const float*)d_in[5];
  const float* sm_fcW    = (const float*)d_in[6];
  const float* sm_fcb    = (const float*)d_in[7];
  const float* ctx_convW = (const float*)d_in[8];
  const float* ctx_convb = (const float*)d_in[9];
  const float* ctx_fcW   = (const float*)d_in[10];
  const float* ctx_fcb   = (const float*)d_in[11];
  const float* attnW     = (const float*)d_in[12];
  const float* attnb     = (const float*)d_in[13];
  const float* probW     = (const float*)d_in[14];
  const float* W1        = (const float*)d_in[15];
  const float* b1        = (const float*)d_in[16];
  const float* gamma     = (const float*)d_in[17];
  const float* beta      = (const float*)d_in[18];
  const float* W2        = (const float*)d_in[19];
  const float* b2        = (const float*)d_in[20];

  float* out = (float*)d_out;   // [0:128) preds, [128:128+64*512) feat_out
  float* ws  = (float*)d_ws;

  // workspace layout with lifetime-based reuse (~39.1 MiB total)
  size_t o = 0;
  float* sent1 = ws + o; o += (size_t)Bn * QLn * Dn;   // 768000
  float* sent2 = ws + o; o += (size_t)Bn * ALn * Dn;   // 1152000
  float* nq    = ws + o; o += Bn * QLn;                // 2560
  float* na    = ws + o; o += Bn * ALn;                // 3840
  float* wreg  = ws + o; o += 2 * (size_t)Dn * W3;     // 460800 (weights; reused post-GEMM)
  float* z1reg = ws + o; o += (size_t)Bn * QLn * W3;   // 1966080 (Z1; reused)
  float* z2reg = ws + o; o += (size_t)Bn * ALn * W3;   // 2949120 (Z2; reused)
  float* S2W   = ws + o; o += (size_t)Bn * ALn * W3;   // 2949120

  float* smWfull   = wreg;
  float* ctxWfull  = wreg + (size_t)Dn * W3;
  // wreg reuse (after the three big GEMMs are done with the weights):
  float* pooled_sm = wreg;                    // 128*256
  float* features  = wreg + 32768;            // 128*256
  float* feat_comb = wreg + 65536;            // 64*768
  float* hmat      = wreg + 65536 + 49152;    // 64*512
  // z1reg reuse (Z1 consumed by k_pool_sm):
  float* Z1         = z1reg;
  float* cosb       = z1reg;                  // 153600
  float* pooled_ctx = z1reg + 153600;         // 655360
  // z2reg reuse (Z2 consumed by k_pool_sm):
  float* Z2      = z2reg;
  float* qa_comb = z2reg;                            // 2560*556
  float* hidden  = z2reg + (size_t)2560 * 556;       // 655360
  float* score   = z2reg + (size_t)2560 * 556 + 655360; // 2560

  // 1. gather + norms
  k_gather<<<Bn * QLn + Bn * ALn, 64, 0, stream>>>(question, answer, embedding,
                                                   sent1, sent2, nq, na);
  // 2. repack conv weights
  int rep = (Kn * Dn * Cn + 255) / 256;
  k_repack<<<rep, 256, 0, stream>>>(sm_convW, smWfull);
  k_repack<<<rep, 256, 0, stream>>>(ctx_convW, ctxWfull);
  // 3. big GEMMs: Z1, Z2, S2W
  dim3 gz1(40, 12), gz2(60, 12);
  k_gemm<<<gz1, 256, 0, stream>>>(sent1, smWfull, Z1, 2560, 768, 300, 300, 768, 768, nullptr, 0);
  k_gemm<<<gz2, 256, 0, stream>>>(sent2, smWfull, Z2, 3840, 768, 300, 300, 768, 768, nullptr, 0);
  k_gemm<<<gz2, 256, 0, stream>>>(sent2, ctxWfull, S2W, 3840, 768, 300, 300, 768, 768, nullptr, 0);
  // 4. sm conv combine + pool (question & answer)
  k_pool_sm<<<128, 256, 0, stream>>>(Z1, Z2, sm_convb, pooled_sm);
  // 5. shared fc -> feature1|feature2
  dim3 gf(2, 4);
  k_gemm<<<gf, 256, 0, stream>>>(pooled_sm, sm_fcW, features, 128, 256, 256, 256, 256, 256, sm_fcb, 0);
  // 6. cosine matrix
  k_cos<<<Bn * QLn, 64, 0, stream>>>(sent1, sent2, nq, na, cosb);
  // 7. ctx conv combine + pool
  k_ctx<<<Bn * QLn, 256, 0, stream>>>(S2W, cosb, ctx_convb, pooled_ctx);
  // 8. ctx fc -> feat (into qa_comb cols 0..255, ldc=556)
  dim3 gc(40, 4);
  k_gemm<<<gc, 256, 0, stream>>>(pooled_ctx, ctx_fcW, qa_comb, 2560, 256, 256, 256, 256, 556, ctx_fcb, 0);
  // 9. sent1 into qa_comb cols 256..555
  k_copy_s1<<<(Bn * QLn * Dn + 255) / 256, 256, 0, stream>>>(sent1, qa_comb);
  // 10. attn MLP hidden = tanh(qa_comb @ attnW + attnb)
  k_gemm<<<gc, 256, 0, stream>>>(qa_comb, attnW, hidden, 2560, 256, 556, 556, 256, 256, attnb, 1);
  // 11. score
  k_score<<<Bn * QLn, 256, 0, stream>>>(hidden, probW, score);
  // 12. softmax + feature3 (into feat_comb cols 512..767)
  k_attnpool<<<Bn, 256, 0, stream>>>(score, qa_comb, feat_comb);
  // 13. feature1|feature2 into feat_comb cols 0..511
  k_concat12<<<(Bn * 512 + 255) / 256, 256, 0, stream>>>(features, feat_comb);
  // 14. h = feat_comb @ W1 + b1
  dim3 gh(1, 8);
  k_gemm<<<gh, 256, 0, stream>>>(feat_comb, W1, hmat, 64, 512, 768, 768, 512, 512, b1, 0);
  // 15. batchnorm + tanh -> feat_out (output 1)
  k_bn_tanh<<<HLUn, 64, 0, stream>>>(hmat, gamma, beta, out + 128);
  // 16. head -> preds (output 0)
  k_head<<<Bn, 64, 0, stream>>>(out + 128, W2, b2, out);
}

// Round 3
// 498.168 us; speedup vs baseline: 1.0632x; 1.0632x over previous
//
#include <hip/hip_runtime.h>
#include <math.h>

#define Bn 64
#define QLn 40
#define ALn 60
#define Dn 300
#define HLUn 512

typedef __attribute__((ext_vector_type(8))) short bf16x8;
typedef __attribute__((ext_vector_type(4))) float f32x4;

__device__ __forceinline__ float bf2f(unsigned short s) {
  return __uint_as_float(((unsigned)s) << 16);
}
__device__ __forceinline__ short f2bf(float f) {
  unsigned u = __float_as_uint(f);
  unsigned r = (u + 0x7FFFu + ((u >> 16) & 1u)) >> 16;
  return (short)r;
}

// ============ gather embeddings -> split-bf16 Ae rows + norms ============
// Ae row layout (Ke=960): [hi(0:320) | lo(320:640) | hi(640:960)], k'>=300 zero
__global__ void k_gather(const int* __restrict__ q, const int* __restrict__ a,
                         const float* __restrict__ emb,
                         short* __restrict__ Ae1, short* __restrict__ Ae2,
                         float* __restrict__ nq, float* __restrict__ na) {
  int row = blockIdx.x;
  const int* idxp; short* Ae; float* nrm; int r;
  if (row < Bn * QLn) { idxp = q; Ae = Ae1; nrm = nq; r = row; }
  else { idxp = a; Ae = Ae2; nrm = na; r = row - Bn * QLn; }
  int tok = idxp[r];
  const float* src = emb + (size_t)tok * Dn;
  short* d = Ae + (size_t)r * 960;
  float ssq = 0.f;
  for (int i = threadIdx.x; i < 320; i += 64) {
    float v = (i < Dn) ? src[i] : 0.f;
    ssq += v * v;
    short hi = f2bf(v);
    short lo = f2bf(v - bf2f((unsigned short)hi));
    d[i] = hi; d[320 + i] = lo; d[640 + i] = hi;
  }
  #pragma unroll
  for (int off = 32; off; off >>= 1) ssq += __shfl_down(ssq, off, 64);
  if (threadIdx.x == 0) nrm[r] = sqrtf(ssq);
}

// ============ conv weights (K=3,D=300,C=256) x2 -> BTconv[1536][960] ============
// BT row layout (B-phase convention): [hi | hi | lo]
__global__ void k_repack_conv(const float* __restrict__ smW, const float* __restrict__ ctxW,
                              short* __restrict__ bt) {
  int i = blockIdx.x * 256 + threadIdx.x;
  if (i >= 1536 * 320) return;
  int n = i / 320, k = i % 320;
  float v = 0.f;
  if (k < 300) {
    const float* w = (n < 768) ? smW : ctxW;
    int j = (n < 768) ? n : n - 768;
    int kk = j >> 8, c = j & 255;
    v = w[(size_t)kk * 300 * 256 + (size_t)k * 256 + c];
  }
  short hi = f2bf(v), lo = f2bf(v - bf2f((unsigned short)hi));
  short* d = bt + (size_t)n * 960;
  d[k] = hi; d[320 + k] = hi; d[640 + k] = lo;
}

// ============ fc-style weight [K][N] fp32 -> BT [N][3*Kp] ============
__global__ void k_wprep(const float* __restrict__ w, short* __restrict__ bt,
                        int K, int N, int Kp) {
  int i = blockIdx.x * 256 + threadIdx.x;
  if (i >= N * Kp) return;
  int n = i / Kp, k = i % Kp;
  float v = (k < K) ? w[(size_t)k * N + n] : 0.f;
  short hi = f2bf(v), lo = f2bf(v - bf2f((unsigned short)hi));
  short* d = bt + (size_t)n * (size_t)(3 * Kp);
  d[k] = hi; d[Kp + k] = hi; d[2 * Kp + k] = lo;
}

// ============ activation fp32 [M][K] (lda) -> Ae [M][3*Kp] ============
__global__ void k_actprep(const float* __restrict__ src, short* __restrict__ dst,
                          int M, int K, int lda, int Kp) {
  int i = blockIdx.x * 256 + threadIdx.x;
  if (i >= M * Kp) return;
  int r = i / Kp, j = i % Kp;
  float v = (j < K) ? src[(size_t)r * lda + j] : 0.f;
  short hi = f2bf(v), lo = f2bf(v - bf2f((unsigned short)hi));
  short* d = dst + (size_t)r * (size_t)(3 * Kp);
  d[j] = hi; d[Kp + j] = lo; d[2 * Kp + j] = hi;
}

// ============ MFMA GEMM: C[M][N](ldc) = act(A[M][Ka] @ BT[N][Ka]^T + bias) ============
// A, BT bf16 (split-phase encoded). 128x128 tile, 4 waves, 16x16x32 MFMA.
__global__ __launch_bounds__(256) void k_mgemm(
    const short* __restrict__ A, const short* __restrict__ BT,
    float* __restrict__ C, int M, int N, int Ka, int ldc,
    const float* __restrict__ bias, int act) {
  __shared__ short As[128][40];   // +8 pad: 2-way-max LDS banking
  __shared__ short Bs[128][40];
  int tid = threadIdx.x;
  int wid = tid >> 6, lane = tid & 63;
  int l15 = lane & 15, l4 = lane >> 4;
  int rowBase = blockIdx.x * 128;
  int colBase = blockIdx.y * 128;
  int mw = wid * 32;

  f32x4 acc[2][8];
  #pragma unroll
  for (int i = 0; i < 2; ++i)
    #pragma unroll
    for (int j = 0; j < 8; ++j) acc[i][j] = (f32x4){0.f, 0.f, 0.f, 0.f};

  for (int k0 = 0; k0 < Ka; k0 += 32) {
    // stage A tile 128x32 (2 chunks of 8 bf16 per thread)
    #pragma unroll
    for (int j = 0; j < 2; ++j) {
      int e = tid + j * 256;
      int r = e >> 2, kc = (e & 3) << 3;
      uint4 val = make_uint4(0u, 0u, 0u, 0u);
      int gr = rowBase + r;
      if (gr < M) val = *reinterpret_cast<const uint4*>(A + (size_t)gr * Ka + k0 + kc);
      *reinterpret_cast<uint4*>(&As[r][kc]) = val;
    }
    // stage B tile 128x32
    #pragma unroll
    for (int j = 0; j < 2; ++j) {
      int e = tid + j * 256;
      int r = e >> 2, kc = (e & 3) << 3;
      uint4 val = *reinterpret_cast<const uint4*>(BT + (size_t)(colBase + r) * Ka + k0 + kc);
      *reinterpret_cast<uint4*>(&Bs[r][kc]) = val;
    }
    __syncthreads();
    bf16x8 a0 = *reinterpret_cast<const bf16x8*>(&As[mw + l15][l4 << 3]);
    bf16x8 a1 = *reinterpret_cast<const bf16x8*>(&As[mw + 16 + l15][l4 << 3]);
    #pragma unroll
    for (int nj = 0; nj < 8; ++nj) {
      bf16x8 bf = *reinterpret_cast<const bf16x8*>(&Bs[nj * 16 + l15][l4 << 3]);
      acc[0][nj] = __builtin_amdgcn_mfma_f32_16x16x32_bf16(a0, bf, acc[0][nj], 0, 0, 0);
      acc[1][nj] = __builtin_amdgcn_mfma_f32_16x16x32_bf16(a1, bf, acc[1][nj], 0, 0, 0);
    }
    __syncthreads();
  }
  // epilogue: C/D layout col=lane&15, row=(lane>>4)*4+reg
  #pragma unroll
  for (int mi = 0; mi < 2; ++mi) {
    int row0 = rowBase + mw + mi * 16 + l4 * 4;
    #pragma unroll
    for (int nj = 0; nj < 8; ++nj) {
      int col = colBase + nj * 16 + l15;
      float bv = bias ? bias[col] : 0.f;
      #pragma unroll
      for (int r = 0; r < 4; ++r) {
        int row = row0 + r;
        if (row < M) {
          float v = acc[mi][nj][r] + bv;
          if (act == 1) v = tanhf(v);
          C[(size_t)row * ldc + col] = v;
        }
      }
    }
  }
}

// ============ sm conv 3-tap combine + relu + maxpool over t ============
__global__ void k_pool_sm(const float* __restrict__ Z1, const float* __restrict__ Z2,
                          const float* __restrict__ convb, float* __restrict__ pooled) {
  int blk = blockIdx.x;  // 0..63 question, 64..127 answer
  int c = threadIdx.x;
  const float* Z; int n, L;
  if (blk < Bn) { Z = Z1; n = blk; L = QLn; }
  else          { Z = Z2; n = blk - Bn; L = ALn; }
  float bias = convb[c];
  const float* base = Z + (size_t)n * L * 768;
  float m = 0.f;
  for (int t = 0; t <= L - 3; ++t) {
    float v = bias + base[t * 768 + c] + base[(t + 1) * 768 + 256 + c]
                   + base[(t + 2) * 768 + 512 + c];
    m = fmaxf(m, v);
  }
  pooled[(size_t)blk * 256 + c] = m;
}

// ============ cosine matrix from split-bf16 rows ============
__global__ void k_cos(const short* __restrict__ Ae1, const short* __restrict__ Ae2,
                      const float* __restrict__ nq, const float* __restrict__ na,
                      float* __restrict__ cosb) {
  int bq = blockIdx.x;
  int b = bq / QLn;
  __shared__ float s1row[304];
  int t = threadIdx.x;
  if (t < 38) {
    const unsigned short* p1 = (const unsigned short*)(Ae1 + (size_t)bq * 960);
    uint4 h = *reinterpret_cast<const uint4*>(p1 + t * 8);
    uint4 l = *reinterpret_cast<const uint4*>(p1 + 320 + t * 8);
    unsigned hs[4] = {h.x, h.y, h.z, h.w}, ls[4] = {l.x, l.y, l.z, l.w};
    #pragma unroll
    for (int j = 0; j < 4; ++j) {
      s1row[t * 8 + j * 2]     = __uint_as_float(hs[j] << 16) + __uint_as_float(ls[j] << 16);
      s1row[t * 8 + j * 2 + 1] = __uint_as_float(hs[j] & 0xFFFF0000u) + __uint_as_float(ls[j] & 0xFFFF0000u);
    }
  }
  __syncthreads();
  int a = threadIdx.x;
  if (a < ALn) {
    const unsigned short* p2 = (const unsigned short*)(Ae2 + ((size_t)b * ALn + a) * 960);
    float dot = 0.f;
    for (int c = 0; c < 38; ++c) {
      uint4 h = *reinterpret_cast<const uint4*>(p2 + c * 8);
      uint4 l = *reinterpret_cast<const uint4*>(p2 + 320 + c * 8);
      unsigned hs[4] = {h.x, h.y, h.z, h.w}, ls[4] = {l.x, l.y, l.z, l.w};
      #pragma unroll
      for (int j = 0; j < 4; ++j) {
        float e0 = __uint_as_float(hs[j] << 16) + __uint_as_float(ls[j] << 16);
        float e1 = __uint_as_float(hs[j] & 0xFFFF0000u) + __uint_as_float(ls[j] & 0xFFFF0000u);
        dot += s1row[c * 8 + j * 2] * e0 + s1row[c * 8 + j * 2 + 1] * e1;
      }
    }
    float den = fmaxf(nq[bq] * na[(size_t)b * ALn + a], 1e-6f);
    cosb[(size_t)bq * ALn + a] = dot / den;
  }
}

// ============ ctx conv = cos-gated 3-tap + relu + maxpool (5 q's per block) ============
__global__ void k_ctx(const float* __restrict__ S2W, const float* __restrict__ cosb,
                      const float* __restrict__ ctxb, float* __restrict__ pooled_ctx) {
  int b = blockIdx.x;   // 0..63
  int qg = blockIdx.y;  // 0..7
  int c = threadIdx.x;
  __shared__ float cl[5][ALn];
  for (int i = threadIdx.x; i < 5 * ALn; i += 256) {
    int qq = i / ALn, tt = i % ALn;
    cl[qq][tt] = cosb[((size_t)b * QLn + qg * 5 + qq) * ALn + tt];
  }
  __syncthreads();
  const float* base = S2W + (size_t)b * ALn * 768;
  float bias = ctxb[c];
  float m[5] = {0.f, 0.f, 0.f, 0.f, 0.f};
  for (int t = 0; t <= ALn - 3; ++t) {
    float v0 = base[t * 768 + c];
    float v1 = base[(t + 1) * 768 + 256 + c];
    float v2 = base[(t + 2) * 768 + 512 + c];
    #pragma unroll
    for (int qq = 0; qq < 5; ++qq) {
      float v = bias + cl[qq][t] * v0 + cl[qq][t + 1] * v1 + cl[qq][t + 2] * v2;
      m[qq] = fmaxf(m[qq], v);
    }
  }
  #pragma unroll
  for (int qq = 0; qq < 5; ++qq)
    pooled_ctx[((size_t)b * QLn + qg * 5 + qq) * 256 + c] = m[qq];
}

// ============ sent1 (reconstructed) -> qa_comb cols 256..555 ============
__global__ void k_copy_s1(const short* __restrict__ Ae1, float* __restrict__ qa) {
  int i = blockIdx.x * 256 + threadIdx.x;
  if (i >= Bn * QLn * Dn) return;
  int r = i / Dn, j = i % Dn;
  const unsigned short* p = (const unsigned short*)(Ae1 + (size_t)r * 960);
  float v = __uint_as_float(((unsigned)p[j]) << 16) + __uint_as_float(((unsigned)p[320 + j]) << 16);
  qa[(size_t)r * 556 + 256 + j] = v;
}

// ============ score = hidden @ probW ============
__global__ void k_score(const float* __restrict__ hidden, const float* __restrict__ probW,
                        float* __restrict__ score) {
  int r = blockIdx.x;
  float v = hidden[(size_t)r * 256 + threadIdx.x] * probW[threadIdx.x];
  #pragma unroll
  for (int off = 32; off; off >>= 1) v += __shfl_down(v, off, 64);
  __shared__ float wsum[4];
  if ((threadIdx.x & 63) == 0) wsum[threadIdx.x >> 6] = v;
  __syncthreads();
  if (threadIdx.x == 0) score[r] = wsum[0] + wsum[1] + wsum[2] + wsum[3];
}

// ============ softmax over q + weighted feat pool -> feat_comb[:,512:768] ============
__global__ void k_attnpool(const float* __restrict__ score, const float* __restrict__ qa,
                           float* __restrict__ feat_comb) {
  int b = blockIdx.x;
  __shared__ float p[QLn];
  __shared__ float inv;
  if (threadIdx.x == 0) {
    float mx = -1e30f;
    for (int qq = 0; qq < QLn; ++qq) mx = fmaxf(mx, score[b * QLn + qq]);
    float den = 0.f;
    for (int qq = 0; qq < QLn; ++qq) {
      float e = expf(score[b * QLn + qq] - mx);
      p[qq] = e; den += e;
    }
    inv = 1.f / den;
  }
  __syncthreads();
  int c = threadIdx.x;
  float acc = 0.f;
  for (int qq = 0; qq < QLn; ++qq)
    acc += p[qq] * qa[((size_t)b * QLn + qq) * 556 + c];
  feat_comb[(size_t)b * 768 + 512 + c] = acc * inv;
}

// ============ feature1|feature2 -> feat_comb cols 0..511 ============
__global__ void k_concat12(const float* __restrict__ features, float* __restrict__ feat_comb) {
  int i = blockIdx.x * 256 + threadIdx.x;
  if (i >= Bn * 512) return;
  int n = i >> 9, j = i & 511;
  float v = (j < 256) ? features[n * 256 + j] : features[(Bn + n) * 256 + (j - 256)];
  feat_comb[(size_t)n * 768 + j] = v;
}

// ============ batchnorm (training stats) + tanh ============
__global__ void k_bn_tanh(const float* __restrict__ h, const float* __restrict__ gamma,
                          const float* __restrict__ beta, float* __restrict__ outp) {
  int j = blockIdx.x;
  int n = threadIdx.x;
  float v = h[(size_t)n * HLUn + j];
  float s = v;
  #pragma unroll
  for (int off = 32; off; off >>= 1) s += __shfl_down(s, off, 64);
  float mu = __shfl(s, 0, 64) * (1.f / 64.f);
  float d = v - mu;
  float s2 = d * d;
  #pragma unroll
  for (int off = 32; off; off >>= 1) s2 += __shfl_down(s2, off, 64);
  float var = __shfl(s2, 0, 64) * (1.f / 64.f);
  float y = d * rsqrtf(var + 1e-5f) * gamma[j] + beta[j];
  outp[(size_t)n * HLUn + j] = tanhf(y);
}

// ============ head: 2-class logits + log_softmax ============
__global__ void k_head(const float* __restrict__ feat_out, const float* __restrict__ W2,
                       const float* __restrict__ b2, float* __restrict__ preds) {
  int n = blockIdx.x;
  int tid = threadIdx.x;
  float a0 = 0.f, a1 = 0.f;
  for (int j = tid; j < HLUn; j += 64) {
    float f = feat_out[(size_t)n * HLUn + j];
    a0 += f * W2[j * 2 + 0];
    a1 += f * W2[j * 2 + 1];
  }
  #pragma unroll
  for (int off = 32; off; off >>= 1) {
    a0 += __shfl_down(a0, off, 64);
    a1 += __shfl_down(a1, off, 64);
  }
  if (tid == 0) {
    float l0 = a0 + b2[0], l1 = a1 + b2[1];
    float mx = fmaxf(l0, l1);
    float lse = mx + logf(expf(l0 - mx) + expf(l1 - mx));
    preds[n * 2 + 0] = l0 - lse;
    preds[n * 2 + 1] = l1 - lse;
  }
}

extern "C" void kernel_launch(void* const* d_in, const int* in_sizes, int n_in,
                              void* d_out, int out_size, void* d_ws, size_t ws_size,
                              hipStream_t stream) {
  (void)in_sizes; (void)n_in; (void)out_size; (void)ws_size;
  const int*   question  = (const int*)d_in[0];
  const int*   answer    = (const int*)d_in[1];
  const float* embedding = (const float*)d_in[3];
  const float* sm_convW  = (const float*)d_in[4];
  const float* sm_convb  = (const float*)d_in[5];
  const float* sm_fcW    = (const float*)d_in[6];
  const float* sm_fcb    = (const float*)d_in[7];
  const float* ctx_convW = (const float*)d_in[8];
  const float* ctx_convb = (const float*)d_in[9];
  const float* ctx_fcW   = (const float*)d_in[10];
  const float* ctx_fcb   = (const float*)d_in[11];
  const float* attnW     = (const float*)d_in[12];
  const float* attnb     = (const float*)d_in[13];
  const float* probW     = (const float*)d_in[14];
  const float* W1        = (const float*)d_in[15];
  const float* b1        = (const float*)d_in[16];
  const float* gamma     = (const float*)d_in[17];
  const float* beta      = (const float*)d_in[18];
  const float* W2        = (const float*)d_in[19];
  const float* b2        = (const float*)d_in[20];

  float* out = (float*)d_out;   // [0:128) preds, [128:) feat_out 64x512
  char* base = (char*)d_ws;
  size_t off = 0;
  auto alloc = [&](size_t bytes) { char* p = base + off; off += (bytes + 255) & ~(size_t)255; return p; };

  short* Ae1    = (short*)alloc(2560ull * 960 * 2);   // sent1 split-bf16
  short* Ae2    = (short*)alloc(3840ull * 960 * 2);   // sent2 split-bf16 (BTconv follows!)
  short* BTconv = (short*)alloc(1536ull * 960 * 2);   // [smW | ctxW] transposed split
  char*  z1reg  = alloc(2560ull * 768 * 4);           // Z1 -> later qa_comb + smalls
  char*  z2reg  = alloc(3840ull * 768 * 4);           // Z2 -> later S2W
  float* nq     = (float*)alloc(2560 * 4);
  float* na     = (float*)alloc(3840 * 4);
  float* cosb   = (float*)alloc(2560ull * 60 * 4);
  float* pooled_sm  = (float*)alloc(128ull * 256 * 4);
  float* features   = (float*)alloc(128ull * 256 * 4);
  float* pooled_ctx = (float*)alloc(2560ull * 256 * 4);
  float* hidden     = (float*)alloc(2560ull * 256 * 4);
  short* BT_fc    = (short*)alloc(256ull * 768 * 2);
  short* BT_ctxfc = (short*)alloc(256ull * 768 * 2);
  short* BT_attn  = (short*)alloc(256ull * 1728 * 2);
  short* BT_w1    = (short*)alloc(512ull * 2304 * 2);

  // overlays (lifetime-disjoint)
  float* Z1  = (float*)z1reg;
  float* Z2  = (float*)z2reg;
  float* S2W = (float*)z2reg;                          // after pool_sm
  float* qa_comb   = (float*)z1reg;                    // after pool_sm: 2560x556
  char*  z1tail    = z1reg + 5693440;
  short* Ae_sm     = (short*)z1tail;                   // 128x768 sh = 196608 B
  short* Ae_fc     = (short*)(z1tail + 196608);        // 64x2304 sh = 294912 B
  float* feat_comb = (float*)(z1tail + 196608 + 294912);          // 64x768
  float* hmat      = (float*)(z1tail + 196608 + 294912 + 196608); // 64x512
  float* score     = (float*)(z1tail + 196608 + 294912 + 196608 + 131072); // 2560
  short* Ae_pctx = (short*)Ae1;                        // after k_cos & copy_s1: 2560x768 sh
  short* Ae_qa   = (short*)Ae2;                        // after k_cos & S2W gemm: 2560x1728 sh
                                                       // (spills into BTconv region: 8.85MB <= 10.3MB)

  // 1. gather -> Ae1, Ae2, norms
  k_gather<<<2560 + 3840, 64, 0, stream>>>(question, answer, embedding, Ae1, Ae2, nq, na);
  // 2. weight preps
  k_repack_conv<<<(1536 * 320 + 255) / 256, 256, 0, stream>>>(sm_convW, ctx_convW, BTconv);
  k_wprep<<<(256 * 256 + 255) / 256, 256, 0, stream>>>(sm_fcW, BT_fc, 256, 256, 256);
  k_wprep<<<(256 * 256 + 255) / 256, 256, 0, stream>>>(ctx_fcW, BT_ctxfc, 256, 256, 256);
  k_wprep<<<(256 * 576 + 255) / 256, 256, 0, stream>>>(attnW, BT_attn, 556, 256, 576);
  k_wprep<<<(512 * 768 + 255) / 256, 256, 0, stream>>>(W1, BT_w1, 768, 512, 768);
  // 3. big MFMA GEMMs
  { dim3 g(20, 6); k_mgemm<<<g, 256, 0, stream>>>(Ae1, BTconv, Z1, 2560, 768, 960, 768, nullptr, 0); }
  { dim3 g(30, 6); k_mgemm<<<g, 256, 0, stream>>>(Ae2, BTconv, Z2, 3840, 768, 960, 768, nullptr, 0); }
  // 4. sm pool (consumes Z1, Z2)
  k_pool_sm<<<128, 256, 0, stream>>>(Z1, Z2, sm_convb, pooled_sm);
  // 5. S2W GEMM (into dead Z2 region)
  { dim3 g(30, 6); k_mgemm<<<g, 256, 0, stream>>>(Ae2, BTconv + 768ull * 960, S2W, 3840, 768, 960, 768, nullptr, 0); }
  // 6. cosine matrix
  k_cos<<<2560, 64, 0, stream>>>(Ae1, Ae2, nq, na, cosb);
  // 7. ctx pool (consumes S2W)
  { dim3 g(64, 8); k_ctx<<<g, 256, 0, stream>>>(S2W, cosb, ctx_convb, pooled_ctx); }
  // 8. features = pooled_sm @ fcW + fcb
  k_actprep<<<(128 * 256 + 255) / 256, 256, 0, stream>>>(pooled_sm, Ae_sm, 128, 256, 256, 256);
  { dim3 g(1, 2); k_mgemm<<<g, 256, 0, stream>>>(Ae_sm, BT_fc, features, 128, 256, 768, 256, sm_fcb, 0); }
  // 9. sent1 -> qa_comb cols 256..555 (Ae1 last read here + k_cos)
  k_copy_s1<<<(2560 * 300 + 255) / 256, 256, 0, stream>>>(Ae1, qa_comb);
  // 10. feat = pooled_ctx @ ctx_fcW + b -> qa_comb cols 0..255
  k_actprep<<<(2560 * 256 + 255) / 256, 256, 0, stream>>>(pooled_ctx, Ae_pctx, 2560, 256, 256, 256);
  { dim3 g(20, 2); k_mgemm<<<g, 256, 0, stream>>>(Ae_pctx, BT_ctxfc, qa_comb, 2560, 256, 768, 556, ctx_fcb, 0); }
  // 11. hidden = tanh(qa_comb @ attnW + attnb)
  k_actprep<<<(2560 * 576 + 255) / 256, 256, 0, stream>>>(qa_comb, Ae_qa, 2560, 556, 556, 576);
  { dim3 g(20, 2); k_mgemm<<<g, 256, 0, stream>>>(Ae_qa, BT_attn, hidden, 2560, 256, 1728, 256, attnb, 1); }
  // 12. score, softmax-pool, concat
  k_score<<<2560, 256, 0, stream>>>(hidden, probW, score);
  k_attnpool<<<64, 256, 0, stream>>>(score, qa_comb, feat_comb);
  k_concat12<<<(64 * 512 + 255) / 256, 256, 0, stream>>>(features, feat_comb);
  // 13. h = feat_comb @ W1 + b1
  k_actprep<<<(64 * 768 + 255) / 256, 256, 0, stream>>>(feat_comb, Ae_fc, 64, 768, 768, 768);
  { dim3 g(1, 4); k_mgemm<<<g, 256, 0, stream>>>(Ae_fc, BT_w1, hmat, 64, 512, 2304, 512, b1, 0); }
  // 14. BN + tanh -> feat_out; head -> preds
  k_bn_tanh<<<HLUn, 64, 0, stream>>>(hmat, gamma, beta, out + 128);
  k_head<<<64, 64, 0, stream>>>(out + 128, W2, b2, out);
}

// Round 4
// 190.443 us; speedup vs baseline: 2.7812x; 2.6158x over previous
//
#include <hip/hip_runtime.h>
#include <math.h>

#define Bn 64
#define QLn 40
#define ALn 60
#define Dn 300
#define KA 960      /* 3 x 320 split-bf16 encoded K */
#define NBIG 1792   /* 768 sm-conv | 768 ctx-conv | 256 attnW2 */
#define MBIG 6400   /* 2560 question rows | 3840 answer rows */

typedef __attribute__((ext_vector_type(8))) short bf16x8;
typedef __attribute__((ext_vector_type(4))) float f32x4;

__device__ __forceinline__ float bf2f(unsigned short s) {
  return __uint_as_float(((unsigned)s) << 16);
}
__device__ __forceinline__ short f2bf(float f) {
  unsigned u = __float_as_uint(f);
  unsigned r = (u + 0x7FFFu + ((u >> 16) & 1u)) >> 16;
  return (short)r;
}

// ============ gather embeddings -> split-bf16 rows [hi|lo|hi] + norms ============
__global__ void k_gather(const int* __restrict__ q, const int* __restrict__ a,
                         const float* __restrict__ emb,
                         short* __restrict__ Ae1, short* __restrict__ Ae2,
                         float* __restrict__ nq, float* __restrict__ na) {
  int row = blockIdx.x;
  const int* idxp; short* Ae; float* nrm; int r;
  if (row < Bn * QLn) { idxp = q; Ae = Ae1; nrm = nq; r = row; }
  else { idxp = a; Ae = Ae2; nrm = na; r = row - Bn * QLn; }
  int tok = idxp[r];
  const float* src = emb + (size_t)tok * Dn;
  short* d = Ae + (size_t)r * KA;
  float ssq = 0.f;
  for (int i = threadIdx.x; i < 320; i += 64) {
    float v = (i < Dn) ? src[i] : 0.f;
    ssq += v * v;
    short hi = f2bf(v);
    short lo = f2bf(v - bf2f((unsigned short)hi));
    d[i] = hi; d[320 + i] = lo; d[640 + i] = hi;
  }
  #pragma unroll
  for (int off = 32; off; off >>= 1) ssq += __shfl_down(ssq, off, 64);
  if (threadIdx.x == 0) nrm[r] = sqrtf(ssq);
}

// ============ BTbig prep: rows [smConv(768) | ctxConv(768) | attnW2(256)], [hi|hi|lo] ============
__global__ void k_btprep(const float* __restrict__ smW, const float* __restrict__ ctxW,
                         const float* __restrict__ attnW, short* __restrict__ bt) {
  int i = blockIdx.x * 256 + threadIdx.x;
  if (i >= NBIG * 320) return;
  int n = i / 320, k = i % 320;
  float v = 0.f;
  if (k < 300) {
    if (n < 1536) {
      const float* w = (n < 768) ? smW : ctxW;
      int j = (n < 768) ? n : n - 768;
      int kk = j >> 8, c = j & 255;
      v = w[(size_t)kk * 76800 + (size_t)k * 256 + c];
    } else {
      v = attnW[(size_t)(256 + k) * 256 + (n - 1536)];   // sent1-part of attn MLP
    }
  }
  short hi = f2bf(v), lo = f2bf(v - bf2f((unsigned short)hi));
  short* d = bt + (size_t)n * KA;
  d[k] = hi; d[320 + k] = hi; d[640 + k] = lo;
}

// ============ mega MFMA GEMM: Zbig[6400][1792] = A[6400][960] @ BT[1792][960]^T ============
// global_load_lds(16B) staging, linear LDS, XOR slot swizzle (2-way max banking).
__device__ __forceinline__ void gl2lds16(const short* g, short* l) {
  __builtin_amdgcn_global_load_lds(
      (const __attribute__((address_space(1))) unsigned int*)g,
      (__attribute__((address_space(3))) unsigned int*)l, 16, 0, 0);
}

__global__ __launch_bounds__(256) void k_mega(
    const short* __restrict__ A, const short* __restrict__ BT,
    float* __restrict__ C) {
  __shared__ __align__(16) short As[128 * 32];
  __shared__ __align__(16) short Bs[128 * 32];
  int tid = threadIdx.x;
  int wid = tid >> 6, lane = tid & 63;
  int l15 = lane & 15, l4 = lane >> 4;
  int rowBase = blockIdx.x * 128;   // gridDim.x = 50
  int colBase = blockIdx.y * 128;   // gridDim.y = 14
  int mw = wid * 32;

  f32x4 acc[2][8];
  #pragma unroll
  for (int i = 0; i < 2; ++i)
    #pragma unroll
    for (int j = 0; j < 8; ++j) acc[i][j] = (f32x4){0.f, 0.f, 0.f, 0.f};

  // read-side swizzled slot indices (row-dependent XOR, involution with source side)
  int rowA0 = mw + l15, rowA1 = mw + 16 + l15;
  int sA0 = (l4 ^ ((rowA0 >> 1) & 3)) << 3;
  int sA1 = (l4 ^ ((rowA1 >> 1) & 3)) << 3;

  for (int k0 = 0; k0 < KA; k0 += 32) {
    #pragma unroll
    for (int j = 0; j < 2; ++j) {
      int idx = tid + j * 256;          // 0..511 chunk id
      int r = idx >> 2, s = idx & 3;
      int sl = s ^ ((r >> 1) & 3);      // inverse-swizzled source slot
      int chunkStart = j * 256 + wid * 64;
      gl2lds16(A + (size_t)(rowBase + r) * KA + k0 + (sl << 3), &As[chunkStart * 8]);
      gl2lds16(BT + (size_t)(colBase + r) * KA + k0 + (sl << 3), &Bs[chunkStart * 8]);
    }
    __syncthreads();   // compiler emits vmcnt(0) drain before barrier
    bf16x8 a0 = *reinterpret_cast<const bf16x8*>(&As[rowA0 * 32 + sA0]);
    bf16x8 a1 = *reinterpret_cast<const bf16x8*>(&As[rowA1 * 32 + sA1]);
    #pragma unroll
    for (int nj = 0; nj < 8; ++nj) {
      int rb = nj * 16 + l15;
      bf16x8 bf = *reinterpret_cast<const bf16x8*>(&Bs[rb * 32 + ((l4 ^ ((rb >> 1) & 3)) << 3)]);
      acc[0][nj] = __builtin_amdgcn_mfma_f32_16x16x32_bf16(a0, bf, acc[0][nj], 0, 0, 0);
      acc[1][nj] = __builtin_amdgcn_mfma_f32_16x16x32_bf16(a1, bf, acc[1][nj], 0, 0, 0);
    }
    __syncthreads();
  }
  #pragma unroll
  for (int mi = 0; mi < 2; ++mi) {
    int row0 = rowBase + mw + mi * 16 + l4 * 4;
    #pragma unroll
    for (int nj = 0; nj < 8; ++nj) {
      int col = colBase + nj * 16 + l15;
      #pragma unroll
      for (int r = 0; r < 4; ++r)
        C[(size_t)(row0 + r) * NBIG + col] = acc[mi][nj][r];
    }
  }
}

// ============ sm conv 3-tap + relu + maxpool ============
__global__ void k_pool_sm(const float* __restrict__ Zbig, const float* __restrict__ convb,
                          float* __restrict__ pooled) {
  int blk = blockIdx.x;  // 0..63 question, 64..127 answer
  int c = threadIdx.x;
  const float* base; int L;
  if (blk < Bn) { base = Zbig + (size_t)blk * QLn * NBIG; L = QLn; }
  else          { base = Zbig + (size_t)(2560 + (blk - Bn) * ALn) * NBIG; L = ALn; }
  float bias = convb[c];
  float m = 0.f;
  for (int t = 0; t <= L - 3; ++t) {
    float v = bias + base[t * NBIG + c] + base[(t + 1) * NBIG + 256 + c]
                   + base[(t + 2) * NBIG + 512 + c];
    m = fmaxf(m, v);
  }
  pooled[(size_t)blk * 256 + c] = m;
}

// ============ cosine matrix from split-bf16 rows ============
__global__ void k_cos(const short* __restrict__ Ae1, const short* __restrict__ Ae2,
                      const float* __restrict__ nq, const float* __restrict__ na,
                      float* __restrict__ cosb) {
  int bq = blockIdx.x;
  int b = bq / QLn;
  __shared__ float s1row[304];
  int t = threadIdx.x;
  if (t < 38) {
    const unsigned short* p1 = (const unsigned short*)(Ae1 + (size_t)bq * KA);
    uint4 h = *reinterpret_cast<const uint4*>(p1 + t * 8);
    uint4 l = *reinterpret_cast<const uint4*>(p1 + 320 + t * 8);
    unsigned hs[4] = {h.x, h.y, h.z, h.w}, ls[4] = {l.x, l.y, l.z, l.w};
    #pragma unroll
    for (int j = 0; j < 4; ++j) {
      s1row[t * 8 + j * 2]     = __uint_as_float(hs[j] << 16) + __uint_as_float(ls[j] << 16);
      s1row[t * 8 + j * 2 + 1] = __uint_as_float(hs[j] & 0xFFFF0000u) + __uint_as_float(ls[j] & 0xFFFF0000u);
    }
  }
  __syncthreads();
  int a = threadIdx.x;
  if (a < ALn) {
    const unsigned short* p2 = (const unsigned short*)(Ae2 + ((size_t)b * ALn + a) * KA);
    float dot = 0.f;
    for (int c = 0; c < 38; ++c) {
      uint4 h = *reinterpret_cast<const uint4*>(p2 + c * 8);
      uint4 l = *reinterpret_cast<const uint4*>(p2 + 320 + c * 8);
      unsigned hs[4] = {h.x, h.y, h.z, h.w}, ls[4] = {l.x, l.y, l.z, l.w};
      #pragma unroll
      for (int j = 0; j < 4; ++j) {
        float e0 = __uint_as_float(hs[j] << 16) + __uint_as_float(ls[j] << 16);
        float e1 = __uint_as_float(hs[j] & 0xFFFF0000u) + __uint_as_float(ls[j] & 0xFFFF0000u);
        dot += s1row[c * 8 + j * 2] * e0 + s1row[c * 8 + j * 2 + 1] * e1;
      }
    }
    float den = fmaxf(nq[bq] * na[(size_t)b * ALn + a], 1e-6f);
    cosb[(size_t)bq * ALn + a] = dot / den;
  }
}

// ============ ctx conv = cos-gated 3-tap + relu + maxpool (10 q's per block) ============
__global__ void k_ctx(const float* __restrict__ Zbig, const float* __restrict__ cosb,
                      const float* __restrict__ ctxb, float* __restrict__ pooled_ctx) {
  int b = blockIdx.x;   // 0..63
  int qg = blockIdx.y;  // 0..3
  int c = threadIdx.x;
  __shared__ float cl[10][ALn];
  for (int i = threadIdx.x; i < 10 * ALn; i += 256) {
    int qq = i / ALn, tt = i % ALn;
    cl[qq][tt] = cosb[((size_t)b * QLn + qg * 10 + qq) * ALn + tt];
  }
  __syncthreads();
  const float* base = Zbig + (size_t)(2560 + b * ALn) * NBIG + 768;  // S2W panel
  float bias = ctxb[c];
  float m[10];
  #pragma unroll
  for (int qq = 0; qq < 10; ++qq) m[qq] = 0.f;
  for (int t = 0; t <= ALn - 3; ++t) {
    float v0 = base[t * NBIG + c];
    float v1 = base[(t + 1) * NBIG + 256 + c];
    float v2 = base[(t + 2) * NBIG + 512 + c];
    #pragma unroll
    for (int qq = 0; qq < 10; ++qq) {
      float v = bias + cl[qq][t] * v0 + cl[qq][t + 1] * v1 + cl[qq][t + 2] * v2;
      m[qq] = fmaxf(m[qq], v);
    }
  }
  #pragma unroll
  for (int qq = 0; qq < 10; ++qq)
    pooled_ctx[((size_t)b * QLn + qg * 10 + qq) * 256 + c] = m[qq];
}

// ============ fc: features = pooled_sm @ sm_fcW + b -> feat_comb cols 0..511 ============
__global__ __launch_bounds__(256) void k_fc(const float* __restrict__ pooled,
                                            const float* __restrict__ W,
                                            const float* __restrict__ bias,
                                            float* __restrict__ feat_comb) {
  int r0 = blockIdx.x * 8;   // 16 blocks x 8 rows
  int j = threadIdx.x;
  __shared__ float xinT[256][8];
  #pragma unroll
  for (int rr = 0; rr < 8; ++rr) xinT[j][rr] = pooled[(size_t)(r0 + rr) * 256 + j];
  __syncthreads();
  float acc[8];
  #pragma unroll
  for (int rr = 0; rr < 8; ++rr) acc[rr] = bias[j];
  for (int k = 0; k < 256; ++k) {
    float w = W[(size_t)k * 256 + j];
    float4 x0 = *reinterpret_cast<const float4*>(&xinT[k][0]);   // broadcast b128
    float4 x1 = *reinterpret_cast<const float4*>(&xinT[k][4]);
    acc[0] += x0.x * w; acc[1] += x0.y * w; acc[2] += x0.z * w; acc[3] += x0.w * w;
    acc[4] += x1.x * w; acc[5] += x1.y * w; acc[6] += x1.z * w; acc[7] += x1.w * w;
  }
  #pragma unroll
  for (int rr = 0; rr < 8; ++rr) {
    int row = r0 + rr;
    feat_comb[(size_t)(row & 63) * 768 + ((row >> 6) * 256) + j] = acc[rr];
  }
}

// ============ fused ctx-fc + attn-MLP + score (8 rows/block, 320 blocks) ============
__global__ __launch_bounds__(256) void k_ctxattn(
    const float* __restrict__ pooled_ctx, const float* __restrict__ Zbig,
    const float* __restrict__ ctxfcW, const float* __restrict__ ctxfcb,
    const float* __restrict__ attnW, const float* __restrict__ attnb,
    const float* __restrict__ probW,
    float* __restrict__ feat, float* __restrict__ score) {
  int r0 = blockIdx.x * 8;
  int j = threadIdx.x;
  __shared__ float xinT[256][8];
  __shared__ float sred[8][4];
  #pragma unroll
  for (int rr = 0; rr < 8; ++rr) xinT[j][rr] = pooled_ctx[(size_t)(r0 + rr) * 256 + j];
  __syncthreads();
  float acc[8];
  #pragma unroll
  for (int rr = 0; rr < 8; ++rr) acc[rr] = ctxfcb[j];
  for (int k = 0; k < 256; ++k) {
    float w = ctxfcW[(size_t)k * 256 + j];
    float4 x0 = *reinterpret_cast<const float4*>(&xinT[k][0]);
    float4 x1 = *reinterpret_cast<const float4*>(&xinT[k][4]);
    acc[0] += x0.x * w; acc[1] += x0.y * w; acc[2] += x0.z * w; acc[3] += x0.w * w;
    acc[4] += x1.x * w; acc[5] += x1.y * w; acc[6] += x1.z * w; acc[7] += x1.w * w;
  }
  __syncthreads();
  #pragma unroll
  for (int rr = 0; rr < 8; ++rr) {
    feat[(size_t)(r0 + rr) * 256 + j] = acc[rr];
    xinT[j][rr] = acc[rr];
  }
  __syncthreads();
  float h[8];
  #pragma unroll
  for (int rr = 0; rr < 8; ++rr)
    h[rr] = attnb[j] + Zbig[(size_t)(r0 + rr) * NBIG + 1536 + j];   // + sent1@attnW2 partial
  for (int k = 0; k < 256; ++k) {
    float w = attnW[(size_t)k * 256 + j];
    float4 x0 = *reinterpret_cast<const float4*>(&xinT[k][0]);
    float4 x1 = *reinterpret_cast<const float4*>(&xinT[k][4]);
    h[0] += x0.x * w; h[1] += x0.y * w; h[2] += x0.z * w; h[3] += x0.w * w;
    h[4] += x1.x * w; h[5] += x1.y * w; h[6] += x1.z * w; h[7] += x1.w * w;
  }
  float pw = probW[j];
  int lane = j & 63, wid = j >> 6;
  #pragma unroll
  for (int rr = 0; rr < 8; ++rr) {
    float s = tanhf(h[rr]) * pw;
    #pragma unroll
    for (int off = 32; off; off >>= 1) s += __shfl_down(s, off, 64);
    if (lane == 0) sred[rr][wid] = s;
  }
  __syncthreads();
  if (j < 8) score[r0 + j] = sred[j][0] + sred[j][1] + sred[j][2] + sred[j][3];
}

// ============ softmax over q + weighted feat pool -> feat_comb[:,512:768] ============
__global__ void k_attnpool(const float* __restrict__ score, const float* __restrict__ feat,
                           float* __restrict__ feat_comb) {
  int b = blockIdx.x;
  __shared__ float p[QLn];
  __shared__ float inv;
  if (threadIdx.x == 0) {
    float mx = -1e30f;
    for (int qq = 0; qq < QLn; ++qq) mx = fmaxf(mx, score[b * QLn + qq]);
    float den = 0.f;
    for (int qq = 0; qq < QLn; ++qq) {
      float e = expf(score[b * QLn + qq] - mx);
      p[qq] = e; den += e;
    }
    inv = 1.f / den;
  }
  __syncthreads();
  int c = threadIdx.x;
  float acc = 0.f;
  for (int qq = 0; qq < QLn; ++qq)
    acc += p[qq] * feat[((size_t)b * QLn + qq) * 256 + c];
  feat_comb[(size_t)b * 768 + 512 + c] = acc * inv;
}

// ============ fused W1 + bias + BatchNorm + tanh (8 cols/block, 64 blocks) ============
__global__ __launch_bounds__(256) void k_w1bn(
    const float* __restrict__ feat_comb, const float* __restrict__ W1,
    const float* __restrict__ b1, const float* __restrict__ gamma,
    const float* __restrict__ beta, float* __restrict__ feat_out) {
  int j0 = blockIdx.x * 8;
  int tid = threadIdx.x;
  __shared__ float wl[768][12];   // pad 8->12 floats: 48B rows, 16B aligned, conflict-spread
  __shared__ float hb[64][8];
  for (int it = 0; it < 24; ++it) {
    int idx = tid + it * 256;
    int k = idx >> 3, jj = idx & 7;
    wl[k][jj] = W1[(size_t)k * 512 + j0 + jj];
  }
  __syncthreads();
  int n = tid >> 2, p = tid & 3;   // 64 rows x 4 interleaved k-chunks
  float acc[8] = {0.f, 0.f, 0.f, 0.f, 0.f, 0.f, 0.f, 0.f};
  const float* frow = feat_comb + (size_t)n * 768 + p;
  for (int i = 0; i < 192; ++i) {
    float v = frow[i * 4];
    int k = p + i * 4;
    float4 w0 = *reinterpret_cast<const float4*>(&wl[k][0]);
    float4 w1v = *reinterpret_cast<const float4*>(&wl[k][4]);
    acc[0] += v * w0.x; acc[1] += v * w0.y; acc[2] += v * w0.z; acc[3] += v * w0.w;
    acc[4] += v * w1v.x; acc[5] += v * w1v.y; acc[6] += v * w1v.z; acc[7] += v * w1v.w;
  }
  #pragma unroll
  for (int jj = 0; jj < 8; ++jj) {
    acc[jj] += __shfl_xor(acc[jj], 1, 64);
    acc[jj] += __shfl_xor(acc[jj], 2, 64);
  }
  if (p == 0) {
    #pragma unroll
    for (int jj = 0; jj < 8; ++jj) hb[n][jj] = acc[jj] + b1[j0 + jj];
  }
  __syncthreads();
  if (tid < 64) {
    #pragma unroll
    for (int jj = 0; jj < 8; ++jj) {
      float v = hb[tid][jj];
      float s = v;
      #pragma unroll
      for (int off = 32; off; off >>= 1) s += __shfl_xor(s, off, 64);
      float mu = s * (1.f / 64.f);
      float d = v - mu;
      float q2 = d * d;
      #pragma unroll
      for (int off = 32; off; off >>= 1) q2 += __shfl_xor(q2, off, 64);
      float var = q2 * (1.f / 64.f);
      feat_out[(size_t)tid * 512 + j0 + jj] =
          tanhf(d * rsqrtf(var + 1e-5f) * gamma[j0 + jj] + beta[j0 + jj]);
    }
  }
}

// ============ head: 2-class logits + log_softmax ============
__global__ void k_head(const float* __restrict__ feat_out, const float* __restrict__ W2,
                       const float* __restrict__ b2, float* __restrict__ preds) {
  int n = blockIdx.x;
  int tid = threadIdx.x;
  float a0 = 0.f, a1 = 0.f;
  for (int j = tid; j < 512; j += 64) {
    float f = feat_out[(size_t)n * 512 + j];
    a0 += f * W2[j * 2 + 0];
    a1 += f * W2[j * 2 + 1];
  }
  #pragma unroll
  for (int off = 32; off; off >>= 1) {
    a0 += __shfl_down(a0, off, 64);
    a1 += __shfl_down(a1, off, 64);
  }
  if (tid == 0) {
    float l0 = a0 + b2[0], l1 = a1 + b2[1];
    float mx = fmaxf(l0, l1);
    float lse = mx + logf(expf(l0 - mx) + expf(l1 - mx));
    preds[n * 2 + 0] = l0 - lse;
    preds[n * 2 + 1] = l1 - lse;
  }
}

extern "C" void kernel_launch(void* const* d_in, const int* in_sizes, int n_in,
                              void* d_out, int out_size, void* d_ws, size_t ws_size,
                              hipStream_t stream) {
  (void)in_sizes; (void)n_in; (void)out_size; (void)ws_size;
  const int*   question  = (const int*)d_in[0];
  const int*   answer    = (const int*)d_in[1];
  const float* embedding = (const float*)d_in[3];
  const float* sm_convW  = (const float*)d_in[4];
  const float* sm_convb  = (const float*)d_in[5];
  const float* sm_fcW    = (const float*)d_in[6];
  const float* sm_fcb    = (const float*)d_in[7];
  const float* ctx_convW = (const float*)d_in[8];
  const float* ctx_convb = (const float*)d_in[9];
  const float* ctx_fcW   = (const float*)d_in[10];
  const float* ctx_fcb   = (const float*)d_in[11];
  const float* attnW     = (const float*)d_in[12];
  const float* attnb     = (const float*)d_in[13];
  const float* probW     = (const float*)d_in[14];
  const float* W1        = (const float*)d_in[15];
  const float* b1        = (const float*)d_in[16];
  const float* gamma     = (const float*)d_in[17];
  const float* beta      = (const float*)d_in[18];
  const float* W2        = (const float*)d_in[19];
  const float* b2        = (const float*)d_in[20];

  float* out = (float*)d_out;   // [0:128) preds, [128:) feat_out 64x512
  char* base = (char*)d_ws;
  size_t off = 0;
  auto alloc = [&](size_t bytes) { char* p = base + off; off += (bytes + 255) & ~(size_t)255; return p; };

  short* Ae1   = (short*)alloc(2560ull * KA * 2);     // 4.92 MB (Ae2 must follow contiguously)
  short* Ae2   = (short*)alloc(3840ull * KA * 2);     // 7.37 MB
  short* BTbig = (short*)alloc((size_t)NBIG * KA * 2);// 3.44 MB; overlaid after k_mega
  float* Zbig  = (float*)alloc((size_t)MBIG * NBIG * 4); // 45.9 MB
  float* nq    = (float*)alloc(2560 * 4);
  float* na    = (float*)alloc(3840 * 4);
  float* feat      = (float*)alloc(2560ull * 256 * 4);   // 2.62 MB
  float* feat_comb = (float*)alloc(64ull * 768 * 4);
  float* score     = (float*)alloc(2560 * 4);
  // overlays into BTbig (dead after k_mega): cosb(600KB) + pooled_sm(128KB) + pooled_ctx(2.56MB)
  float* cosb       = (float*)BTbig;
  float* pooled_sm  = (float*)((char*)BTbig + 655360);
  float* pooled_ctx = (float*)((char*)BTbig + 655360 + 131072);

  // 1. gather -> split-bf16 rows + norms
  k_gather<<<MBIG, 64, 0, stream>>>(question, answer, embedding, Ae1, Ae2, nq, na);
  // 2. BTbig prep
  k_btprep<<<(NBIG * 320 + 255) / 256, 256, 0, stream>>>(sm_convW, ctx_convW, attnW, BTbig);
  // 3. mega GEMM (700 blocks)
  { dim3 g(MBIG / 128, NBIG / 128); k_mega<<<g, 256, 0, stream>>>(Ae1, BTbig, Zbig); }
  // 4. sm pool
  k_pool_sm<<<128, 256, 0, stream>>>(Zbig, sm_convb, pooled_sm);
  // 5. cosine matrix
  k_cos<<<2560, 64, 0, stream>>>(Ae1, Ae2, nq, na, cosb);
  // 6. ctx pool
  { dim3 g(Bn, 4); k_ctx<<<g, 256, 0, stream>>>(Zbig, cosb, ctx_convb, pooled_ctx); }
  // 7. fc -> feat_comb cols 0..511
  k_fc<<<16, 256, 0, stream>>>(pooled_sm, sm_fcW, sm_fcb, feat_comb);
  // 8. fused ctx-fc + attn MLP + score
  k_ctxattn<<<320, 256, 0, stream>>>(pooled_ctx, Zbig, ctx_fcW, ctx_fcb,
                                     attnW, attnb, probW, feat, score);
  // 9. softmax-pool -> feat_comb cols 512..767
  k_attnpool<<<Bn, 256, 0, stream>>>(score, feat, feat_comb);
  // 10. fused W1 + BN + tanh -> feat_out
  k_w1bn<<<64, 256, 0, stream>>>(feat_comb, W1, b1, gamma, beta, out + 128);
  // 11. head -> preds
  k_head<<<Bn, 64, 0, stream>>>(out + 128, W2, b2, out);
}

// Round 5
// 183.295 us; speedup vs baseline: 2.8896x; 1.0390x over previous
//
#include <hip/hip_runtime.h>
#include <math.h>

#define Bn 64
#define QLn 40
#define ALn 60
#define Dn 300
#define KA 960      /* 3 x 320 split-bf16 encoded K */
#define NBIG 1792   /* 768 sm-conv | 768 ctx-conv | 256 attnW2 */
#define MBIG 6400   /* 2560 question rows | 3840 answer rows */

typedef __attribute__((ext_vector_type(8))) short bf16x8;
typedef __attribute__((ext_vector_type(4))) float f32x4;

__device__ __forceinline__ float bf2f(unsigned short s) {
  return __uint_as_float(((unsigned)s) << 16);
}
__device__ __forceinline__ short f2bf(float f) {
  unsigned u = __float_as_uint(f);
  unsigned r = (u + 0x7FFFu + ((u >> 16) & 1u)) >> 16;
  return (short)r;
}

// ============ gather embeddings -> split-bf16 rows [hi|lo|hi] + norms ============
__global__ void k_gather(const int* __restrict__ q, const int* __restrict__ a,
                         const float* __restrict__ emb,
                         short* __restrict__ Ae1, short* __restrict__ Ae2,
                         float* __restrict__ nq, float* __restrict__ na) {
  int row = blockIdx.x;
  const int* idxp; short* Ae; float* nrm; int r;
  if (row < Bn * QLn) { idxp = q; Ae = Ae1; nrm = nq; r = row; }
  else { idxp = a; Ae = Ae2; nrm = na; r = row - Bn * QLn; }
  int tok = idxp[r];
  const float* src = emb + (size_t)tok * Dn;
  short* d = Ae + (size_t)r * KA;
  float ssq = 0.f;
  for (int i = threadIdx.x; i < 320; i += 64) {
    float v = (i < Dn) ? src[i] : 0.f;
    ssq += v * v;
    short hi = f2bf(v);
    short lo = f2bf(v - bf2f((unsigned short)hi));
    d[i] = hi; d[320 + i] = lo; d[640 + i] = hi;
  }
  #pragma unroll
  for (int off = 32; off; off >>= 1) ssq += __shfl_down(ssq, off, 64);
  if (threadIdx.x == 0) nrm[r] = sqrtf(ssq);
}

// ============ BTbig prep: rows [smConv(768) | ctxConv(768) | attnW2(256)], [hi|hi|lo] ============
__global__ void k_btprep(const float* __restrict__ smW, const float* __restrict__ ctxW,
                         const float* __restrict__ attnW, short* __restrict__ bt) {
  int i = blockIdx.x * 256 + threadIdx.x;
  if (i >= NBIG * 320) return;
  int n = i / 320, k = i % 320;
  float v = 0.f;
  if (k < 300) {
    if (n < 1536) {
      const float* w = (n < 768) ? smW : ctxW;
      int j = (n < 768) ? n : n - 768;
      int kk = j >> 8, c = j & 255;
      v = w[(size_t)kk * 76800 + (size_t)k * 256 + c];
    } else {
      v = attnW[(size_t)(256 + k) * 256 + (n - 1536)];   // sent1-part of attn MLP
    }
  }
  short hi = f2bf(v), lo = f2bf(v - bf2f((unsigned short)hi));
  short* d = bt + (size_t)n * KA;
  d[k] = hi; d[320 + k] = hi; d[640 + k] = lo;
}

// ============ Wcat prep: Wcat[k][0:256]=ctxfcW[k][:], Wcat[k][256:512]=(ctxfcW@attnW0)[k][:]
//              block 256: bvec[0:256]=ctxfcb, bvec[256:512]=ctxfcb@attnW0+attnb ============
__global__ __launch_bounds__(256) void k_wcomb(const float* __restrict__ ctxfcW,
                                               const float* __restrict__ ctxfcb,
                                               const float* __restrict__ attnW,
                                               const float* __restrict__ attnb,
                                               float* __restrict__ Wcat,
                                               float* __restrict__ bvec) {
  int k = blockIdx.x;            // 0..256
  int j = threadIdx.x;
  __shared__ float rowv[256];
  rowv[j] = (k < 256) ? ctxfcW[(size_t)k * 256 + j] : ctxfcb[j];
  __syncthreads();
  float acc = 0.f;
  #pragma unroll 4
  for (int m = 0; m < 256; ++m)
    acc += rowv[m] * attnW[(size_t)m * 256 + j];
  if (k < 256) {
    Wcat[(size_t)k * 512 + j] = rowv[j];
    Wcat[(size_t)k * 512 + 256 + j] = acc;
  } else {
    bvec[j] = ctxfcb[j];
    bvec[256 + j] = acc + attnb[j];
  }
}

// ============ mega MFMA GEMM: Zbig[6400][1792] = A @ BT^T ============
__device__ __forceinline__ void gl2lds16(const short* g, short* l) {
  __builtin_amdgcn_global_load_lds(
      (const __attribute__((address_space(1))) unsigned int*)g,
      (__attribute__((address_space(3))) unsigned int*)l, 16, 0, 0);
}

__global__ __launch_bounds__(256) void k_mega(
    const short* __restrict__ A, const short* __restrict__ BT,
    float* __restrict__ C) {
  __shared__ __align__(16) short As[128 * 64];
  __shared__ __align__(16) short Bs[128 * 64];
  int tid = threadIdx.x;
  int wid = tid >> 6, lane = tid & 63;
  int l15 = lane & 15, l4 = lane >> 4;
  // bijective XCD swizzle (700 = 4*88 + 4*87) then 2x14 tile chunking for L2 A-reuse
  int bid = blockIdx.x;
  int xcd = bid & 7, sub = bid >> 3;
  int lin = (xcd < 4) ? xcd * 88 + sub : 352 + (xcd - 4) * 87 + sub;
  int chunk = lin / 28, w = lin % 28;
  int by = w >> 1, bx = chunk * 2 + (w & 1);
  int rowBase = bx * 128;           // bx 0..49
  int colBase = by * 128;           // by 0..13
  int mw = wid * 32;

  f32x4 acc[2][8];
  #pragma unroll
  for (int i = 0; i < 2; ++i)
    #pragma unroll
    for (int j = 0; j < 8; ++j) acc[i][j] = (f32x4){0.f, 0.f, 0.f, 0.f};

  for (int k0 = 0; k0 < KA; k0 += 64) {
    // stage 128x64 tiles; linear LDS dest (chunk idx), inverse-swizzled global slot
    #pragma unroll
    for (int j = 0; j < 4; ++j) {
      int idx = tid + j * 256;            // chunk id 0..1023
      int r = idx >> 3, s = idx & 7;
      int sl = s ^ (r & 7);
      int cbase = (j * 256 + wid * 64) * 8;
      gl2lds16(A + (size_t)(rowBase + r) * KA + k0 + sl * 8, &As[cbase]);
      gl2lds16(BT + (size_t)(colBase + r) * KA + k0 + sl * 8, &Bs[cbase]);
    }
    __syncthreads();
    #pragma unroll
    for (int ks = 0; ks < 2; ++ks) {
      int s = ks * 4 + l4;
      int rowA0 = mw + l15, rowA1 = mw + 16 + l15;
      bf16x8 a0 = *reinterpret_cast<const bf16x8*>(&As[rowA0 * 64 + (s ^ (rowA0 & 7)) * 8]);
      bf16x8 a1 = *reinterpret_cast<const bf16x8*>(&As[rowA1 * 64 + (s ^ (rowA1 & 7)) * 8]);
      #pragma unroll
      for (int nj = 0; nj < 8; ++nj) {
        int rb = nj * 16 + l15;
        bf16x8 bf = *reinterpret_cast<const bf16x8*>(&Bs[rb * 64 + (s ^ (rb & 7)) * 8]);
        acc[0][nj] = __builtin_amdgcn_mfma_f32_16x16x32_bf16(a0, bf, acc[0][nj], 0, 0, 0);
        acc[1][nj] = __builtin_amdgcn_mfma_f32_16x16x32_bf16(a1, bf, acc[1][nj], 0, 0, 0);
      }
    }
    __syncthreads();
  }
  #pragma unroll
  for (int mi = 0; mi < 2; ++mi) {
    int row0 = rowBase + mw + mi * 16 + l4 * 4;
    #pragma unroll
    for (int nj = 0; nj < 8; ++nj) {
      int col = colBase + nj * 16 + l15;
      #pragma unroll
      for (int r = 0; r < 4; ++r)
        C[(size_t)(row0 + r) * NBIG + col] = acc[mi][nj][r];
    }
  }
}

// ============ sm conv 3-tap + relu + maxpool, t-split halves ============
__global__ void k_pool_sm(const float* __restrict__ Zbig, const float* __restrict__ convb,
                          float* __restrict__ pooled_part) {
  int blk = blockIdx.x;   // 0..127
  int half = blockIdx.y;  // 0..1
  int c = threadIdx.x;
  const float* base; int P;
  if (blk < Bn) { base = Zbig + (size_t)blk * QLn * NBIG; P = QLn - 2; }
  else          { base = Zbig + (size_t)(2560 + (blk - Bn) * ALn) * NBIG; P = ALn - 2; }
  int t0 = half * (P >> 1), t1 = (half ? P : (P >> 1));
  float bias = convb[c];
  float m = 0.f;
  #pragma unroll 4
  for (int t = t0; t < t1; ++t) {
    float v = bias + base[t * NBIG + c] + base[(t + 1) * NBIG + 256 + c]
                   + base[(t + 2) * NBIG + 512 + c];
    m = fmaxf(m, v);
  }
  pooled_part[((size_t)half * 128 + blk) * 256 + c] = m;
}

// ============ cosine matrix from split-bf16 rows ============
__global__ void k_cos(const short* __restrict__ Ae1, const short* __restrict__ Ae2,
                      const float* __restrict__ nq, const float* __restrict__ na,
                      float* __restrict__ cosb) {
  int bq = blockIdx.x;
  int b = bq / QLn;
  __shared__ float s1row[304];
  int t = threadIdx.x;
  if (t < 38) {
    const unsigned short* p1 = (const unsigned short*)(Ae1 + (size_t)bq * KA);
    uint4 h = *reinterpret_cast<const uint4*>(p1 + t * 8);
    uint4 l = *reinterpret_cast<const uint4*>(p1 + 320 + t * 8);
    unsigned hs[4] = {h.x, h.y, h.z, h.w}, ls[4] = {l.x, l.y, l.z, l.w};
    #pragma unroll
    for (int j = 0; j < 4; ++j) {
      s1row[t * 8 + j * 2]     = __uint_as_float(hs[j] << 16) + __uint_as_float(ls[j] << 16);
      s1row[t * 8 + j * 2 + 1] = __uint_as_float(hs[j] & 0xFFFF0000u) + __uint_as_float(ls[j] & 0xFFFF0000u);
    }
  }
  __syncthreads();
  int a = threadIdx.x;
  if (a < ALn) {
    const unsigned short* p2 = (const unsigned short*)(Ae2 + ((size_t)b * ALn + a) * KA);
    float dot = 0.f;
    for (int c = 0; c < 38; ++c) {
      uint4 h = *reinterpret_cast<const uint4*>(p2 + c * 8);
      uint4 l = *reinterpret_cast<const uint4*>(p2 + 320 + c * 8);
      unsigned hs[4] = {h.x, h.y, h.z, h.w}, ls[4] = {l.x, l.y, l.z, l.w};
      #pragma unroll
      for (int j = 0; j < 4; ++j) {
        float e0 = __uint_as_float(hs[j] << 16) + __uint_as_float(ls[j] << 16);
        float e1 = __uint_as_float(hs[j] & 0xFFFF0000u) + __uint_as_float(ls[j] & 0xFFFF0000u);
        dot += s1row[c * 8 + j * 2] * e0 + s1row[c * 8 + j * 2 + 1] * e1;
      }
    }
    float den = fmaxf(nq[bq] * na[(size_t)b * ALn + a], 1e-6f);
    cosb[(size_t)bq * ALn + a] = dot / den;
  }
}

// ============ ctx conv: cos-gated 3-tap + relu + maxpool; (qg,t-half) x b grid ============
__global__ void k_ctx(const float* __restrict__ Zbig, const float* __restrict__ cosb,
                      const float* __restrict__ ctxb, float* __restrict__ pctx_part) {
  int sub = blockIdx.x;       // 0..7: qg = sub>>1, th = sub&1
  int b = blockIdx.y;         // 0..63
  int qg = sub >> 1, th = sub & 1;
  int c = threadIdx.x;
  __shared__ float cl[10][ALn];
  for (int i = threadIdx.x; i < 10 * ALn; i += 256) {
    int qq = i / ALn, tt = i % ALn;
    cl[qq][tt] = cosb[((size_t)b * QLn + qg * 10 + qq) * ALn + tt];
  }
  __syncthreads();
  const float* base = Zbig + (size_t)(2560 + b * ALn) * NBIG + 768;  // S2W panel
  float bias = ctxb[c];
  float m[10];
  #pragma unroll
  for (int qq = 0; qq < 10; ++qq) m[qq] = 0.f;
  int t0 = th * 29;
  #pragma unroll 2
  for (int t = t0; t < t0 + 29; ++t) {
    float v0 = base[t * NBIG + c];
    float v1 = base[(t + 1) * NBIG + 256 + c];
    float v2 = base[(t + 2) * NBIG + 512 + c];
    #pragma unroll
    for (int qq = 0; qq < 10; ++qq) {
      float v = bias + cl[qq][t] * v0 + cl[qq][t + 1] * v1 + cl[qq][t + 2] * v2;
      m[qq] = fmaxf(m[qq], v);
    }
  }
  #pragma unroll
  for (int qq = 0; qq < 10; ++qq)
    pctx_part[((size_t)th * 2560 + (size_t)b * QLn + qg * 10 + qq) * 256 + c] = m[qq];
}

// ============ fc: features = max(pooled halves) @ sm_fcW + b -> feat_comb[:,0:512] ============
__global__ __launch_bounds__(256) void k_fc(const float* __restrict__ pooled_part,
                                            const float* __restrict__ W,
                                            const float* __restrict__ bias,
                                            float* __restrict__ feat_comb) {
  int r0 = blockIdx.x * 4;   // 32 blocks x 4 rows
  int j = threadIdx.x;
  __shared__ float xin[256][4];
  __shared__ float wt[32][256];
  #pragma unroll
  for (int rr = 0; rr < 4; ++rr)
    xin[j][rr] = fmaxf(pooled_part[(size_t)(r0 + rr) * 256 + j],
                       pooled_part[(size_t)(128 + r0 + rr) * 256 + j]);
  float acc[4];
  #pragma unroll
  for (int rr = 0; rr < 4; ++rr) acc[rr] = bias[j];
  for (int ph = 0; ph < 8; ++ph) {
    const float4* src = (const float4*)(W + (size_t)ph * 32 * 256);
    float4* dst = (float4*)wt;
    #pragma unroll
    for (int i = 0; i < 8; ++i) dst[i * 256 + j] = src[i * 256 + j];
    __syncthreads();
    #pragma unroll
    for (int kk = 0; kk < 32; ++kk) {
      float4 x = *reinterpret_cast<const float4*>(&xin[ph * 32 + kk][0]);
      float wv = wt[kk][j];
      acc[0] += x.x * wv; acc[1] += x.y * wv; acc[2] += x.z * wv; acc[3] += x.w * wv;
    }
    __syncthreads();
  }
  #pragma unroll
  for (int rr = 0; rr < 4; ++rr) {
    int row = r0 + rr;
    feat_comb[(size_t)(row & 63) * 768 + ((row >> 6) * 256) + j] = acc[rr];
  }
}

// ============ fused feat + hidden + score: one N=512 LDS-staged GEMM ============
__global__ __launch_bounds__(256) void k_ctxattn2(
    const float* __restrict__ pctx_part, const float* __restrict__ Wcat,
    const float* __restrict__ bvec, const float* __restrict__ Zbig,
    const float* __restrict__ probW,
    float* __restrict__ feat, float* __restrict__ score) {
  int r0 = blockIdx.x * 8;   // 320 blocks x 8 rows
  int j = threadIdx.x;
  __shared__ float xin[256][8];
  __shared__ float wt[16][512];
  __shared__ float sred[8][4];
  #pragma unroll
  for (int rr = 0; rr < 8; ++rr)
    xin[j][rr] = fmaxf(pctx_part[(size_t)(r0 + rr) * 256 + j],
                       pctx_part[(size_t)(2560 + r0 + rr) * 256 + j]);
  float hf[8], hh[8];
  float bf0 = bvec[j], bh0 = bvec[256 + j];
  #pragma unroll
  for (int rr = 0; rr < 8; ++rr) {
    hf[rr] = bf0;
    hh[rr] = bh0 + Zbig[(size_t)(r0 + rr) * NBIG + 1536 + j];   // sent1@attnW2 partial
  }
  for (int ph = 0; ph < 16; ++ph) {
    const float4* src = (const float4*)(Wcat + (size_t)ph * 16 * 512);
    float4* dst = (float4*)wt;
    #pragma unroll
    for (int i = 0; i < 8; ++i) dst[i * 256 + j] = src[i * 256 + j];
    __syncthreads();
    #pragma unroll
    for (int kk = 0; kk < 16; ++kk) {
      int k = ph * 16 + kk;
      float4 x0 = *reinterpret_cast<const float4*>(&xin[k][0]);
      float4 x1 = *reinterpret_cast<const float4*>(&xin[k][4]);
      float w0 = wt[kk][j], w1 = wt[kk][256 + j];
      hf[0] += x0.x * w0; hf[1] += x0.y * w0; hf[2] += x0.z * w0; hf[3] += x0.w * w0;
      hf[4] += x1.x * w0; hf[5] += x1.y * w0; hf[6] += x1.z * w0; hf[7] += x1.w * w0;
      hh[0] += x0.x * w1; hh[1] += x0.y * w1; hh[2] += x0.z * w1; hh[3] += x0.w * w1;
      hh[4] += x1.x * w1; hh[5] += x1.y * w1; hh[6] += x1.z * w1; hh[7] += x1.w * w1;
    }
    __syncthreads();
  }
  #pragma unroll
  for (int rr = 0; rr < 8; ++rr)
    feat[(size_t)(r0 + rr) * 256 + j] = hf[rr];
  float pw = probW[j];
  int lane = j & 63, wv = j >> 6;
  #pragma unroll
  for (int rr = 0; rr < 8; ++rr) {
    float s = tanhf(hh[rr]) * pw;
    #pragma unroll
    for (int off = 32; off; off >>= 1) s += __shfl_down(s, off, 64);
    if (lane == 0) sred[rr][wv] = s;
  }
  __syncthreads();
  if (j < 8) score[r0 + j] = sred[j][0] + sred[j][1] + sred[j][2] + sred[j][3];
}

// ============ softmax over q + weighted feat pool -> feat_comb[:,512:768] ============
__global__ void k_attnpool(const float* __restrict__ score, const float* __restrict__ feat,
                           float* __restrict__ feat_comb) {
  int b = blockIdx.x;
  int tid = threadIdx.x;
  __shared__ float p[QLn];
  __shared__ float inv;
  if (tid < 64) {
    float sc = (tid < QLn) ? score[b * QLn + tid] : -1e30f;
    float mx = sc;
    #pragma unroll
    for (int off = 32; off; off >>= 1) mx = fmaxf(mx, __shfl_xor(mx, off, 64));
    float e = (tid < QLn) ? expf(sc - mx) : 0.f;
    if (tid < QLn) p[tid] = e;
    float den = e;
    #pragma unroll
    for (int off = 32; off; off >>= 1) den += __shfl_xor(den, off, 64);
    if (tid == 0) inv = 1.f / den;
  }
  __syncthreads();
  float acc = 0.f;
  for (int qq = 0; qq < QLn; ++qq)
    acc += p[qq] * feat[((size_t)b * QLn + qq) * 256 + tid];
  feat_comb[(size_t)b * 768 + 512 + tid] = acc * inv;
}

// ============ fused W1 + bias + BatchNorm + tanh ============
__global__ __launch_bounds__(256) void k_w1bn(
    const float* __restrict__ feat_comb, const float* __restrict__ W1,
    const float* __restrict__ b1, const float* __restrict__ gamma,
    const float* __restrict__ beta, float* __restrict__ feat_out) {
  int j0 = blockIdx.x * 8;
  int tid = threadIdx.x;
  __shared__ float wl[768][12];
  __shared__ float hb[64][8];
  for (int it = 0; it < 24; ++it) {
    int idx = tid + it * 256;
    int k = idx >> 3, jj = idx & 7;
    wl[k][jj] = W1[(size_t)k * 512 + j0 + jj];
  }
  __syncthreads();
  int n = tid >> 2, p = tid & 3;
  float acc[8] = {0.f, 0.f, 0.f, 0.f, 0.f, 0.f, 0.f, 0.f};
  const float* frow = feat_comb + (size_t)n * 768 + p;
  for (int i = 0; i < 192; ++i) {
    float v = frow[i * 4];
    int k = p + i * 4;
    float4 w0 = *reinterpret_cast<const float4*>(&wl[k][0]);
    float4 w1v = *reinterpret_cast<const float4*>(&wl[k][4]);
    acc[0] += v * w0.x; acc[1] += v * w0.y; acc[2] += v * w0.z; acc[3] += v * w0.w;
    acc[4] += v * w1v.x; acc[5] += v * w1v.y; acc[6] += v * w1v.z; acc[7] += v * w1v.w;
  }
  #pragma unroll
  for (int jj = 0; jj < 8; ++jj) {
    acc[jj] += __shfl_xor(acc[jj], 1, 64);
    acc[jj] += __shfl_xor(acc[jj], 2, 64);
  }
  if (p == 0) {
    #pragma unroll
    for (int jj = 0; jj < 8; ++jj) hb[n][jj] = acc[jj] + b1[j0 + jj];
  }
  __syncthreads();
  if (tid < 64) {
    #pragma unroll
    for (int jj = 0; jj < 8; ++jj) {
      float v = hb[tid][jj];
      float s = v;
      #pragma unroll
      for (int off = 32; off; off >>= 1) s += __shfl_xor(s, off, 64);
      float mu = s * (1.f / 64.f);
      float d = v - mu;
      float q2 = d * d;
      #pragma unroll
      for (int off = 32; off; off >>= 1) q2 += __shfl_xor(q2, off, 64);
      float var = q2 * (1.f / 64.f);
      feat_out[(size_t)tid * 512 + j0 + jj] =
          tanhf(d * rsqrtf(var + 1e-5f) * gamma[j0 + jj] + beta[j0 + jj]);
    }
  }
}

// ============ head: 2-class logits + log_softmax ============
__global__ void k_head(const float* __restrict__ feat_out, const float* __restrict__ W2,
                       const float* __restrict__ b2, float* __restrict__ preds) {
  int n = blockIdx.x;
  int tid = threadIdx.x;
  float a0 = 0.f, a1 = 0.f;
  for (int j = tid; j < 512; j += 64) {
    float f = feat_out[(size_t)n * 512 + j];
    a0 += f * W2[j * 2 + 0];
    a1 += f * W2[j * 2 + 1];
  }
  #pragma unroll
  for (int off = 32; off; off >>= 1) {
    a0 += __shfl_down(a0, off, 64);
    a1 += __shfl_down(a1, off, 64);
  }
  if (tid == 0) {
    float l0 = a0 + b2[0], l1 = a1 + b2[1];
    float mx = fmaxf(l0, l1);
    float lse = mx + logf(expf(l0 - mx) + expf(l1 - mx));
    preds[n * 2 + 0] = l0 - lse;
    preds[n * 2 + 1] = l1 - lse;
  }
}

extern "C" void kernel_launch(void* const* d_in, const int* in_sizes, int n_in,
                              void* d_out, int out_size, void* d_ws, size_t ws_size,
                              hipStream_t stream) {
  (void)in_sizes; (void)n_in; (void)out_size; (void)ws_size;
  const int*   question  = (const int*)d_in[0];
  const int*   answer    = (const int*)d_in[1];
  const float* embedding = (const float*)d_in[3];
  const float* sm_convW  = (const float*)d_in[4];
  const float* sm_convb  = (const float*)d_in[5];
  const float* sm_fcW    = (const float*)d_in[6];
  const float* sm_fcb    = (const float*)d_in[7];
  const float* ctx_convW = (const float*)d_in[8];
  const float* ctx_convb = (const float*)d_in[9];
  const float* ctx_fcW   = (const float*)d_in[10];
  const float* ctx_fcb   = (const float*)d_in[11];
  const float* attnW     = (const float*)d_in[12];
  const float* attnb     = (const float*)d_in[13];
  const float* probW     = (const float*)d_in[14];
  const float* W1        = (const float*)d_in[15];
  const float* b1        = (const float*)d_in[16];
  const float* gamma     = (const float*)d_in[17];
  const float* beta      = (const float*)d_in[18];
  const float* W2        = (const float*)d_in[19];
  const float* b2        = (const float*)d_in[20];

  float* out = (float*)d_out;   // [0:128) preds, [128:) feat_out 64x512
  char* base = (char*)d_ws;
  size_t off = 0;
  auto alloc = [&](size_t bytes) { char* p = base + off; off += (bytes + 255) & ~(size_t)255; return p; };

  short* Ae1   = (short*)alloc(2560ull * KA * 2);
  short* Ae2   = (short*)alloc(3840ull * KA * 2);
  short* BTbig = (short*)alloc((size_t)NBIG * KA * 2);   // dead after k_mega -> overlay
  float* Zbig  = (float*)alloc((size_t)MBIG * NBIG * 4);
  float* nq    = (float*)alloc(2560 * 4);
  float* na    = (float*)alloc(3840 * 4);
  float* Wcat  = (float*)alloc(256ull * 512 * 4);
  float* bvec  = (float*)alloc(512 * 4);
  float* pctx_part = (float*)alloc(2ull * 2560 * 256 * 4);
  float* feat      = (float*)alloc(2560ull * 256 * 4);
  float* feat_comb = (float*)alloc(64ull * 768 * 4);
  float* score     = (float*)alloc(2560 * 4);
  // overlays into BTbig (dead after k_mega)
  float* cosb        = (float*)BTbig;                         // 614KB
  float* pooled_part = (float*)((char*)BTbig + 655360);       // 262KB

  // 1. gather -> split-bf16 rows + norms
  k_gather<<<MBIG, 64, 0, stream>>>(question, answer, embedding, Ae1, Ae2, nq, na);
  // 2. BTbig prep
  k_btprep<<<(NBIG * 320 + 255) / 256, 256, 0, stream>>>(sm_convW, ctx_convW, attnW, BTbig);
  // 3. Wcat = [ctxfcW | ctxfcW@attnW0] + bvec
  k_wcomb<<<257, 256, 0, stream>>>(ctx_fcW, ctx_fcb, attnW, attnb, Wcat, bvec);
  // 4. mega GEMM (700 blocks, swizzled)
  k_mega<<<700, 256, 0, stream>>>(Ae1, BTbig, Zbig);
  // 5. sm pool (t-split halves)
  { dim3 g(128, 2); k_pool_sm<<<g, 256, 0, stream>>>(Zbig, sm_convb, pooled_part); }
  // 6. cosine matrix
  k_cos<<<2560, 64, 0, stream>>>(Ae1, Ae2, nq, na, cosb);
  // 7. ctx pool (qg x t-half x b = 512 blocks)
  { dim3 g(8, 64); k_ctx<<<g, 256, 0, stream>>>(Zbig, cosb, ctx_convb, pctx_part); }
  // 8. fc -> feat_comb cols 0..511
  k_fc<<<32, 256, 0, stream>>>(pooled_part, sm_fcW, sm_fcb, feat_comb);
  // 9. fused feat + hidden + score
  k_ctxattn2<<<320, 256, 0, stream>>>(pctx_part, Wcat, bvec, Zbig, probW, feat, score);
  // 10. softmax-pool -> feat_comb cols 512..767
  k_attnpool<<<Bn, 256, 0, stream>>>(score, feat, feat_comb);
  // 11. fused W1 + BN + tanh -> feat_out
  k_w1bn<<<64, 256, 0, stream>>>(feat_comb, W1, b1, gamma, beta, out + 128);
  // 12. head -> preds
  k_head<<<Bn, 64, 0, stream>>>(out + 128, W2, b2, out);
}

// Round 6
// 161.284 us; speedup vs baseline: 3.2840x; 1.1365x over previous
//
#include <hip/hip_runtime.h>
#include <math.h>

#define Bn 64
#define QLn 40
#define ALn 60
#define Dn 300
#define KA 960       /* 3 x 320 split-bf16 encoded K */
#define NQ 1024      /* Q job cols: 768 sm-conv | 256 attnW2 */
#define NA 1536      /* A job cols: 768 sm-conv | 768 ctx-conv */

typedef __attribute__((ext_vector_type(8))) short bf16x8;
typedef __attribute__((ext_vector_type(4))) float f32x4;

__device__ __forceinline__ float bf2f(unsigned short s) {
  return __uint_as_float(((unsigned)s) << 16);
}
__device__ __forceinline__ short f2bf(float f) {
  unsigned u = __float_as_uint(f);
  unsigned r = (u + 0x7FFFu + ((u >> 16) & 1u)) >> 16;
  return (short)r;
}

// ============ fused prep: gather (1600) | BT prep (3200) | Wcat comb (257) ============
__global__ __launch_bounds__(256) void k_prep(
    const int* __restrict__ q, const int* __restrict__ a, const float* __restrict__ emb,
    const float* __restrict__ smW, const float* __restrict__ ctxW,
    const float* __restrict__ attnW, const float* __restrict__ ctxfcW,
    const float* __restrict__ ctxfcb, const float* __restrict__ attnb,
    short* __restrict__ Ae1, short* __restrict__ Ae2,
    float* __restrict__ nq, float* __restrict__ na,
    short* __restrict__ BTall, float* __restrict__ Wcat, float* __restrict__ bvec) {
  __shared__ float rowv[256];
  int bid = blockIdx.x, tid = threadIdx.x;
  if (bid < 1600) {
    // ---- gather embeddings -> split-bf16 rows [hi|lo|hi] + norms; 1 row per wave ----
    int row = bid * 4 + (tid >> 6);
    int lane = tid & 63;
    const int* idxp; short* Ae; float* nrm; int r;
    if (row < Bn * QLn) { idxp = q; Ae = Ae1; nrm = nq; r = row; }
    else { idxp = a; Ae = Ae2; nrm = na; r = row - Bn * QLn; }
    int tok = idxp[r];
    const float* src = emb + (size_t)tok * Dn;
    short* d = Ae + (size_t)r * KA;
    float ssq = 0.f;
    for (int i = lane; i < 320; i += 64) {
      float v = (i < Dn) ? src[i] : 0.f;
      ssq += v * v;
      short hi = f2bf(v);
      short lo = f2bf(v - bf2f((unsigned short)hi));
      d[i] = hi; d[320 + i] = lo; d[640 + i] = hi;
    }
    #pragma unroll
    for (int off = 32; off; off >>= 1) ssq += __shfl_down(ssq, off, 64);
    if (lane == 0) nrm[r] = sqrtf(ssq);
  } else if (bid < 4800) {
    // ---- BTall rows: [0:768 sm | 768:1024 attnW2 | 1024:1792 sm | 1792:2560 ctx], [hi|hi|lo] ----
    int i = (bid - 1600) * 256 + tid;    // 0..819199 = 2560*320
    int n = i / 320, k = i % 320;
    float v = 0.f;
    if (k < 300) {
      if (n < 768) {
        v = smW[(size_t)(n >> 8) * 76800 + (size_t)k * 256 + (n & 255)];
      } else if (n < 1024) {
        v = attnW[(size_t)(256 + k) * 256 + (n - 768)];
      } else if (n < 1792) {
        int j = n - 1024;
        v = smW[(size_t)(j >> 8) * 76800 + (size_t)k * 256 + (j & 255)];
      } else {
        int j = n - 1792;
        v = ctxW[(size_t)(j >> 8) * 76800 + (size_t)k * 256 + (j & 255)];
      }
    }
    short hi = f2bf(v), lo = f2bf(v - bf2f((unsigned short)hi));
    short* d = BTall + (size_t)n * KA;
    d[k] = hi; d[320 + k] = hi; d[640 + k] = lo;
  } else {
    // ---- Wcat[k] = [ctxfcW[k] | (ctxfcW@attnW0)[k]]; bvec = [ctxfcb | ctxfcb@attnW0+attnb] ----
    int k = bid - 4800;                  // 0..256
    int j = tid;
    rowv[j] = (k < 256) ? ctxfcW[(size_t)k * 256 + j] : ctxfcb[j];
    __syncthreads();
    float acc = 0.f;
    #pragma unroll 4
    for (int m = 0; m < 256; ++m)
      acc += rowv[m] * attnW[(size_t)m * 256 + j];
    if (k < 256) {
      Wcat[(size_t)k * 512 + j] = rowv[j];
      Wcat[(size_t)k * 512 + 256 + j] = acc;
    } else {
      bvec[j] = ctxfcb[j];
      bvec[256 + j] = acc + attnb[j];
    }
  }
}

// ============ split mega MFMA GEMM: ZQ[2560][1024], ZA[3840][1536] ============
__device__ __forceinline__ void gl2lds16(const short* g, short* l) {
  __builtin_amdgcn_global_load_lds(
      (const __attribute__((address_space(1))) unsigned int*)g,
      (__attribute__((address_space(3))) unsigned int*)l, 16, 0, 0);
}

__global__ __launch_bounds__(256) void k_mega(
    const short* __restrict__ Ae1, const short* __restrict__ Ae2,
    const short* __restrict__ BTall, float* __restrict__ ZQ, float* __restrict__ ZA) {
  __shared__ __align__(16) short As[128 * 32];
  __shared__ __align__(16) short Bs[128 * 32];
  int tid = threadIdx.x;
  int wid = tid >> 6, lane = tid & 63;
  int l15 = lane & 15, l4 = lane >> 4;
  // bijective XCD swizzle: 520 blocks = 8 XCDs x 65
  int bid = blockIdx.x;
  int lin = (bid & 7) * 65 + (bid >> 3);
  const short *A, *BT; float* C; int bx, by, ldc;
  if (lin < 160) {            // Q job: 20 x 8 tiles, chunks of 2bx x 8by
    int chunk = lin >> 4, w = lin & 15;
    by = w >> 1; bx = chunk * 2 + (w & 1);
    A = Ae1; BT = BTall; C = ZQ; ldc = NQ;
  } else {                    // A job: 30 x 12 tiles, chunks of 2bx x 12by
    int l2 = lin - 160;
    int chunk = l2 / 24, w = l2 % 24;
    by = w >> 1; bx = chunk * 2 + (w & 1);
    A = Ae2; BT = BTall + (size_t)1024 * KA; C = ZA; ldc = NA;
  }
  int rowBase = bx * 128, colBase = by * 128;
  int mw = wid * 32;

  f32x4 acc[2][8];
  #pragma unroll
  for (int i = 0; i < 2; ++i)
    #pragma unroll
    for (int j = 0; j < 8; ++j) acc[i][j] = (f32x4){0.f, 0.f, 0.f, 0.f};

  int rowA0 = mw + l15, rowA1 = mw + 16 + l15;
  int sA0 = (l4 ^ ((rowA0 >> 1) & 3)) << 3;
  int sA1 = (l4 ^ ((rowA1 >> 1) & 3)) << 3;

  for (int k0 = 0; k0 < KA; k0 += 32) {
    #pragma unroll
    for (int j = 0; j < 2; ++j) {
      int idx = tid + j * 256;          // chunk id 0..511
      int r = idx >> 2, s = idx & 3;
      int sl = s ^ ((r >> 1) & 3);      // inverse-swizzled source slot
      int chunkStart = j * 256 + wid * 64;   // wave-uniform LDS base (lane x16B implicit)
      gl2lds16(A + (size_t)(rowBase + r) * KA + k0 + (sl << 3), &As[chunkStart * 8]);
      gl2lds16(BT + (size_t)(colBase + r) * KA + k0 + (sl << 3), &Bs[chunkStart * 8]);
    }
    __syncthreads();
    bf16x8 a0 = *reinterpret_cast<const bf16x8*>(&As[rowA0 * 32 + sA0]);
    bf16x8 a1 = *reinterpret_cast<const bf16x8*>(&As[rowA1 * 32 + sA1]);
    #pragma unroll
    for (int nj = 0; nj < 8; ++nj) {
      int rb = nj * 16 + l15;
      bf16x8 bf = *reinterpret_cast<const bf16x8*>(&Bs[rb * 32 + ((l4 ^ ((rb >> 1) & 3)) << 3)]);
      acc[0][nj] = __builtin_amdgcn_mfma_f32_16x16x32_bf16(a0, bf, acc[0][nj], 0, 0, 0);
      acc[1][nj] = __builtin_amdgcn_mfma_f32_16x16x32_bf16(a1, bf, acc[1][nj], 0, 0, 0);
    }
    __syncthreads();
  }
  #pragma unroll
  for (int mi = 0; mi < 2; ++mi) {
    int row0 = rowBase + mw + mi * 16 + l4 * 4;
    #pragma unroll
    for (int nj = 0; nj < 8; ++nj) {
      int col = colBase + nj * 16 + l15;
      #pragma unroll
      for (int r = 0; r < 4; ++r)
        C[(size_t)(row0 + r) * ldc + col] = acc[mi][nj][r];
    }
  }
}

// ============ fused: sm pool t-split (256 blocks) | cosine (640 blocks x 4 waves) ============
__global__ void k_poolcos(const float* __restrict__ ZQ, const float* __restrict__ ZA,
                          const float* __restrict__ convb,
                          const short* __restrict__ Ae1, const short* __restrict__ Ae2,
                          const float* __restrict__ nq, const float* __restrict__ na,
                          float* __restrict__ pooled_part, float* __restrict__ cosb) {
  __shared__ float s1row[4][304];
  int bid = blockIdx.x, tid = threadIdx.x;
  if (bid < 256) {
    // ---- sm conv 3-tap + relu + maxpool half ----
    int blk = bid & 127, half = bid >> 7;
    int c = tid;
    const float* base; int P, ld;
    if (blk < Bn) { base = ZQ + (size_t)blk * QLn * NQ; P = QLn - 2; ld = NQ; }
    else          { base = ZA + (size_t)(blk - Bn) * ALn * NA; P = ALn - 2; ld = NA; }
    int t0 = half * (P >> 1), t1 = (half ? P : (P >> 1));
    float bias = convb[c];
    float m = 0.f;
    #pragma unroll 4
    for (int t = t0; t < t1; ++t) {
      float v = bias + base[t * ld + c] + base[(t + 1) * ld + 256 + c]
                     + base[(t + 2) * ld + 512 + c];
      m = fmaxf(m, v);
    }
    pooled_part[((size_t)half * 128 + blk) * 256 + c] = m;
  } else {
    // ---- cosine: wave w handles bq = (bid-256)*4 + w ----
    int w = tid >> 6, lane = tid & 63;
    int bq = (bid - 256) * 4 + w;
    int b = bq / QLn;
    if (lane < 38) {
      const unsigned short* p1 = (const unsigned short*)(Ae1 + (size_t)bq * KA);
      uint4 h = *reinterpret_cast<const uint4*>(p1 + lane * 8);
      uint4 l = *reinterpret_cast<const uint4*>(p1 + 320 + lane * 8);
      unsigned hs[4] = {h.x, h.y, h.z, h.w}, ls[4] = {l.x, l.y, l.z, l.w};
      #pragma unroll
      for (int j = 0; j < 4; ++j) {
        s1row[w][lane * 8 + j * 2]     = __uint_as_float(hs[j] << 16) + __uint_as_float(ls[j] << 16);
        s1row[w][lane * 8 + j * 2 + 1] = __uint_as_float(hs[j] & 0xFFFF0000u) + __uint_as_float(ls[j] & 0xFFFF0000u);
      }
    }
    __syncthreads();
    if (lane < ALn) {
      const unsigned short* p2 = (const unsigned short*)(Ae2 + ((size_t)b * ALn + lane) * KA);
      float dot = 0.f;
      for (int c = 0; c < 38; ++c) {
        uint4 h = *reinterpret_cast<const uint4*>(p2 + c * 8);
        uint4 l = *reinterpret_cast<const uint4*>(p2 + 320 + c * 8);
        unsigned hs[4] = {h.x, h.y, h.z, h.w}, ls[4] = {l.x, l.y, l.z, l.w};
        #pragma unroll
        for (int j = 0; j < 4; ++j) {
          float e0 = __uint_as_float(hs[j] << 16) + __uint_as_float(ls[j] << 16);
          float e1 = __uint_as_float(hs[j] & 0xFFFF0000u) + __uint_as_float(ls[j] & 0xFFFF0000u);
          dot += s1row[w][c * 8 + j * 2] * e0 + s1row[w][c * 8 + j * 2 + 1] * e1;
        }
      }
      float den = fmaxf(nq[bq] * na[(size_t)b * ALn + lane], 1e-6f);
      cosb[(size_t)bq * ALn + lane] = dot / den;
    }
  }
}

// ============ ctx conv: cos-gated 3-tap + relu + maxpool; (qg,t-half) x b ============
__global__ void k_ctx(const float* __restrict__ ZA, const float* __restrict__ cosb,
                      const float* __restrict__ ctxb, float* __restrict__ pctx_part) {
  int sub = blockIdx.x;       // 0..7: qg = sub>>1, th = sub&1
  int b = blockIdx.y;         // 0..63
  int qg = sub >> 1, th = sub & 1;
  int c = threadIdx.x;
  __shared__ float cl[10][ALn];
  for (int i = threadIdx.x; i < 10 * ALn; i += 256) {
    int qq = i / ALn, tt = i % ALn;
    cl[qq][tt] = cosb[((size_t)b * QLn + qg * 10 + qq) * ALn + tt];
  }
  __syncthreads();
  const float* base = ZA + (size_t)b * ALn * NA + 768;   // S2W panel
  float bias = ctxb[c];
  float m[10];
  #pragma unroll
  for (int qq = 0; qq < 10; ++qq) m[qq] = 0.f;
  int t0 = th * 29;
  #pragma unroll 2
  for (int t = t0; t < t0 + 29; ++t) {
    float v0 = base[t * NA + c];
    float v1 = base[(t + 1) * NA + 256 + c];
    float v2 = base[(t + 2) * NA + 512 + c];
    #pragma unroll
    for (int qq = 0; qq < 10; ++qq) {
      float v = bias + cl[qq][t] * v0 + cl[qq][t + 1] * v1 + cl[qq][t + 2] * v2;
      m[qq] = fmaxf(m[qq], v);
    }
  }
  #pragma unroll
  for (int qq = 0; qq < 10; ++qq)
    pctx_part[((size_t)th * 2560 + (size_t)b * QLn + qg * 10 + qq) * 256 + c] = m[qq];
}

// ============ fused: fc (32 blocks) | ctx-fc+attn-MLP+score (320 blocks) ============
__global__ __launch_bounds__(256) void k_fcattn(
    const float* __restrict__ pooled_part, const float* __restrict__ smfcW,
    const float* __restrict__ smfcb,
    const float* __restrict__ pctx_part, const float* __restrict__ Wcat,
    const float* __restrict__ bvec, const float* __restrict__ ZQ,
    const float* __restrict__ probW,
    float* __restrict__ feat_comb, float* __restrict__ feat, float* __restrict__ score) {
  __shared__ float lds[10304];   // union: fc 9216 | attn 10272 floats
  int bid = blockIdx.x, j = threadIdx.x;
  if (bid < 32) {
    // ---- features = max(pool halves) @ sm_fcW + b -> feat_comb cols 0..511 ----
    float* xin = lds;            // [256][4]
    float* wt  = lds + 1024;     // [32][256]
    int r0 = bid * 4;
    #pragma unroll
    for (int rr = 0; rr < 4; ++rr)
      xin[j * 4 + rr] = fmaxf(pooled_part[(size_t)(r0 + rr) * 256 + j],
                              pooled_part[(size_t)(128 + r0 + rr) * 256 + j]);
    float acc[4];
    #pragma unroll
    for (int rr = 0; rr < 4; ++rr) acc[rr] = smfcb[j];
    for (int ph = 0; ph < 8; ++ph) {
      const float4* src = (const float4*)(smfcW + (size_t)ph * 32 * 256);
      float4* dst = (float4*)wt;
      #pragma unroll
      for (int i = 0; i < 8; ++i) dst[i * 256 + j] = src[i * 256 + j];
      __syncthreads();
      #pragma unroll
      for (int kk = 0; kk < 32; ++kk) {
        float4 x = *reinterpret_cast<const float4*>(&xin[(ph * 32 + kk) * 4]);
        float wv = wt[kk * 256 + j];
        acc[0] += x.x * wv; acc[1] += x.y * wv; acc[2] += x.z * wv; acc[3] += x.w * wv;
      }
      __syncthreads();
    }
    #pragma unroll
    for (int rr = 0; rr < 4; ++rr) {
      int row = r0 + rr;
      feat_comb[(size_t)(row & 63) * 768 + ((row >> 6) * 256) + j] = acc[rr];
    }
  } else {
    // ---- feat + hidden + score via Wcat ----
    float* xin  = lds;           // [256][8]
    float* wt   = lds + 2048;    // [16][512]
    float* sred = lds + 10240;   // [8][4]
    int r0 = (bid - 32) * 8;
    #pragma unroll
    for (int rr = 0; rr < 8; ++rr)
      xin[j * 8 + rr] = fmaxf(pctx_part[(size_t)(r0 + rr) * 256 + j],
                              pctx_part[(size_t)(2560 + r0 + rr) * 256 + j]);
    float hf[8], hh[8];
    float bf0 = bvec[j], bh0 = bvec[256 + j];
    #pragma unroll
    for (int rr = 0; rr < 8; ++rr) {
      hf[rr] = bf0;
      hh[rr] = bh0 + ZQ[(size_t)(r0 + rr) * NQ + 768 + j];   // sent1@attnW2 partial
    }
    for (int ph = 0; ph < 16; ++ph) {
      const float4* src = (const float4*)(Wcat + (size_t)ph * 16 * 512);
      float4* dst = (float4*)wt;
      #pragma unroll
      for (int i = 0; i < 8; ++i) dst[i * 256 + j] = src[i * 256 + j];
      __syncthreads();
      #pragma unroll
      for (int kk = 0; kk < 16; ++kk) {
        int k = ph * 16 + kk;
        float4 x0 = *reinterpret_cast<const float4*>(&xin[k * 8]);
        float4 x1 = *reinterpret_cast<const float4*>(&xin[k * 8 + 4]);
        float w0 = wt[kk * 512 + j], w1 = wt[kk * 512 + 256 + j];
        hf[0] += x0.x * w0; hf[1] += x0.y * w0; hf[2] += x0.z * w0; hf[3] += x0.w * w0;
        hf[4] += x1.x * w0; hf[5] += x1.y * w0; hf[6] += x1.z * w0; hf[7] += x1.w * w0;
        hh[0] += x0.x * w1; hh[1] += x0.y * w1; hh[2] += x0.z * w1; hh[3] += x0.w * w1;
        hh[4] += x1.x * w1; hh[5] += x1.y * w1; hh[6] += x1.z * w1; hh[7] += x1.w * w1;
      }
      __syncthreads();
    }
    #pragma unroll
    for (int rr = 0; rr < 8; ++rr)
      feat[(size_t)(r0 + rr) * 256 + j] = hf[rr];
    float pw = probW[j];
    int lane = j & 63, wv = j >> 6;
    #pragma unroll
    for (int rr = 0; rr < 8; ++rr) {
      float s = tanhf(hh[rr]) * pw;
      #pragma unroll
      for (int off = 32; off; off >>= 1) s += __shfl_down(s, off, 64);
      if (lane == 0) sred[rr * 4 + wv] = s;
    }
    __syncthreads();
    if (j < 8) score[r0 + j] = sred[j * 4] + sred[j * 4 + 1] + sred[j * 4 + 2] + sred[j * 4 + 3];
  }
}

// ============ softmax over q + weighted feat pool -> feat_comb[:,512:768] ============
__global__ void k_attnpool(const float* __restrict__ score, const float* __restrict__ feat,
                           float* __restrict__ feat_comb) {
  int b = blockIdx.x;
  int tid = threadIdx.x;
  __shared__ float p[QLn];
  __shared__ float inv;
  if (tid < 64) {
    float sc = (tid < QLn) ? score[b * QLn + tid] : -1e30f;
    float mx = sc;
    #pragma unroll
    for (int off = 32; off; off >>= 1) mx = fmaxf(mx, __shfl_xor(mx, off, 64));
    float e = (tid < QLn) ? expf(sc - mx) : 0.f;
    if (tid < QLn) p[tid] = e;
    float den = e;
    #pragma unroll
    for (int off = 32; off; off >>= 1) den += __shfl_xor(den, off, 64);
    if (tid == 0) inv = 1.f / den;
  }
  __syncthreads();
  float acc = 0.f;
  for (int qq = 0; qq < QLn; ++qq)
    acc += p[qq] * feat[((size_t)b * QLn + qq) * 256 + tid];
  feat_comb[(size_t)b * 768 + 512 + tid] = acc * inv;
}

// ============ fused W1 + bias + BatchNorm + tanh ============
__global__ __launch_bounds__(256) void k_w1bn(
    const float* __restrict__ feat_comb, const float* __restrict__ W1,
    const float* __restrict__ b1, const float* __restrict__ gamma,
    const float* __restrict__ beta, float* __restrict__ feat_out) {
  int j0 = blockIdx.x * 8;
  int tid = threadIdx.x;
  __shared__ float wl[768][12];
  __shared__ float hb[64][8];
  for (int it = 0; it < 24; ++it) {
    int idx = tid + it * 256;
    int k = idx >> 3, jj = idx & 7;
    wl[k][jj] = W1[(size_t)k * 512 + j0 + jj];
  }
  __syncthreads();
  int n = tid >> 2, p = tid & 3;
  float acc[8] = {0.f, 0.f, 0.f, 0.f, 0.f, 0.f, 0.f, 0.f};
  const float* frow = feat_comb + (size_t)n * 768 + p;
  for (int i = 0; i < 192; ++i) {
    float v = frow[i * 4];
    int k = p + i * 4;
    float4 w0 = *reinterpret_cast<const float4*>(&wl[k][0]);
    float4 w1v = *reinterpret_cast<const float4*>(&wl[k][4]);
    acc[0] += v * w0.x; acc[1] += v * w0.y; acc[2] += v * w0.z; acc[3] += v * w0.w;
    acc[4] += v * w1v.x; acc[5] += v * w1v.y; acc[6] += v * w1v.z; acc[7] += v * w1v.w;
  }
  #pragma unroll
  for (int jj = 0; jj < 8; ++jj) {
    acc[jj] += __shfl_xor(acc[jj], 1, 64);
    acc[jj] += __shfl_xor(acc[jj], 2, 64);
  }
  if (p == 0) {
    #pragma unroll
    for (int jj = 0; jj < 8; ++jj) hb[n][jj] = acc[jj] + b1[j0 + jj];
  }
  __syncthreads();
  if (tid < 64) {
    #pragma unroll
    for (int jj = 0; jj < 8; ++jj) {
      float v = hb[tid][jj];
      float s = v;
      #pragma unroll
      for (int off = 32; off; off >>= 1) s += __shfl_xor(s, off, 64);
      float mu = s * (1.f / 64.f);
      float d = v - mu;
      float q2 = d * d;
      #pragma unroll
      for (int off = 32; off; off >>= 1) q2 += __shfl_xor(q2, off, 64);
      float var = q2 * (1.f / 64.f);
      feat_out[(size_t)tid * 512 + j0 + jj] =
          tanhf(d * rsqrtf(var + 1e-5f) * gamma[j0 + jj] + beta[j0 + jj]);
    }
  }
}

// ============ head: 2-class logits + log_softmax ============
__global__ void k_head(const float* __restrict__ feat_out, const float* __restrict__ W2,
                       const float* __restrict__ b2, float* __restrict__ preds) {
  int n = blockIdx.x;
  int tid = threadIdx.x;
  float a0 = 0.f, a1 = 0.f;
  for (int j = tid; j < 512; j += 64) {
    float f = feat_out[(size_t)n * 512 + j];
    a0 += f * W2[j * 2 + 0];
    a1 += f * W2[j * 2 + 1];
  }
  #pragma unroll
  for (int off = 32; off; off >>= 1) {
    a0 += __shfl_down(a0, off, 64);
    a1 += __shfl_down(a1, off, 64);
  }
  if (tid == 0) {
    float l0 = a0 + b2[0], l1 = a1 + b2[1];
    float mx = fmaxf(l0, l1);
    float lse = mx + logf(expf(l0 - mx) + expf(l1 - mx));
    preds[n * 2 + 0] = l0 - lse;
    preds[n * 2 + 1] = l1 - lse;
  }
}

extern "C" void kernel_launch(void* const* d_in, const int* in_sizes, int n_in,
                              void* d_out, int out_size, void* d_ws, size_t ws_size,
                              hipStream_t stream) {
  (void)in_sizes; (void)n_in; (void)out_size; (void)ws_size;
  const int*   question  = (const int*)d_in[0];
  const int*   answer    = (const int*)d_in[1];
  const float* embedding = (const float*)d_in[3];
  const float* sm_convW  = (const float*)d_in[4];
  const float* sm_convb  = (const float*)d_in[5];
  const float* sm_fcW    = (const float*)d_in[6];
  const float* sm_fcb    = (const float*)d_in[7];
  const float* ctx_convW = (const float*)d_in[8];
  const float* ctx_convb = (const float*)d_in[9];
  const float* ctx_fcW   = (const float*)d_in[10];
  const float* ctx_fcb   = (const float*)d_in[11];
  const float* attnW     = (const float*)d_in[12];
  const float* attnb     = (const float*)d_in[13];
  const float* probW     = (const float*)d_in[14];
  const float* W1        = (const float*)d_in[15];
  const float* b1        = (const float*)d_in[16];
  const float* gamma     = (const float*)d_in[17];
  const float* beta      = (const float*)d_in[18];
  const float* W2        = (const float*)d_in[19];
  const float* b2        = (const float*)d_in[20];

  float* out = (float*)d_out;   // [0:128) preds, [128:) feat_out 64x512
  char* base = (char*)d_ws;
  size_t off = 0;
  auto alloc = [&](size_t bytes) { char* p = base + off; off += (bytes + 255) & ~(size_t)255; return p; };

  short* Ae1   = (short*)alloc(2560ull * KA * 2);       // 4.92 MB
  short* Ae2   = (short*)alloc(3840ull * KA * 2);       // 7.37 MB
  short* BTall = (short*)alloc(2560ull * KA * 2);       // 4.92 MB; dead after k_mega -> overlay
  float* ZQ    = (float*)alloc(2560ull * NQ * 4);       // 10.5 MB
  float* ZA    = (float*)alloc(3840ull * NA * 4);       // 23.6 MB
  float* nq    = (float*)alloc(2560 * 4);
  float* na    = (float*)alloc(3840 * 4);
  float* Wcat  = (float*)alloc(256ull * 512 * 4);
  float* bvec  = (float*)alloc(512 * 4);
  float* pctx_part = (float*)alloc(2ull * 2560 * 256 * 4);
  float* feat      = (float*)alloc(2560ull * 256 * 4);
  float* feat_comb = (float*)alloc(64ull * 768 * 4);
  float* score     = (float*)alloc(2560 * 4);
  // overlays into BTall (dead after k_mega)
  float* cosb        = (float*)BTall;                    // 614 KB
  float* pooled_part = (float*)((char*)BTall + 655360);  // 262 KB

  // 1. prep: gather | BT | Wcat  (5057 blocks)
  k_prep<<<5057, 256, 0, stream>>>(question, answer, embedding, sm_convW, ctx_convW,
                                   attnW, ctx_fcW, ctx_fcb, attnb,
                                   Ae1, Ae2, nq, na, BTall, Wcat, bvec);
  // 2. split mega GEMM (520 blocks)
  k_mega<<<520, 256, 0, stream>>>(Ae1, Ae2, BTall, ZQ, ZA);
  // 3. sm pool | cosine  (896 blocks)
  k_poolcos<<<896, 256, 0, stream>>>(ZQ, ZA, sm_convb, Ae1, Ae2, nq, na,
                                     pooled_part, cosb);
  // 4. ctx pool (512 blocks)
  { dim3 g(8, 64); k_ctx<<<g, 256, 0, stream>>>(ZA, cosb, ctx_convb, pctx_part); }
  // 5. fc | ctx-fc+attn+score (352 blocks)
  k_fcattn<<<352, 256, 0, stream>>>(pooled_part, sm_fcW, sm_fcb,
                                    pctx_part, Wcat, bvec, ZQ, probW,
                                    feat_comb, feat, score);
  // 6. softmax-pool -> feat_comb cols 512..767
  k_attnpool<<<Bn, 256, 0, stream>>>(score, feat, feat_comb);
  // 7. fused W1 + BN + tanh -> feat_out
  k_w1bn<<<64, 256, 0, stream>>>(feat_comb, W1, b1, gamma, beta, out + 128);
  // 8. head -> preds
  k_head<<<Bn, 64, 0, stream>>>(out + 128, W2, b2, out);
}

// Round 7
// 157.365 us; speedup vs baseline: 3.3658x; 1.0249x over previous
//
#include <hip/hip_runtime.h>
#include <math.h>

#define Bn 64
#define QLn 40
#define ALn 60
#define Dn 300
#define KS 640       /* stored row width: [hi(320) | lo(320)] */
#define NQ 1024      /* Q job cols: 768 sm-conv | 256 attnW2 */
#define NA 1536      /* A job cols: 768 sm-conv | 768 ctx-conv */

typedef __attribute__((ext_vector_type(8))) short bf16x8;
typedef __attribute__((ext_vector_type(4))) float f32x4;

__device__ __forceinline__ float bf2f(unsigned short s) {
  return __uint_as_float(((unsigned)s) << 16);
}
__device__ __forceinline__ short f2bf(float f) {
  unsigned u = __float_as_uint(f);
  unsigned r = (u + 0x7FFFu + ((u >> 16) & 1u)) >> 16;
  return (short)r;
}

// ============ fused prep ============
// bid [0,256): cosine (b x a-quarter), fp32 direct from embedding
// bid [256,1856): gather -> split-bf16 [hi|lo]
// bid [1856,2056): BT transpose (coalesced, LDS tile)
// bid [2056,2313): Wcat = [ctxfcW | ctxfcW@attnW0] + bvec
__global__ __launch_bounds__(256) void k_prep(
    const int* __restrict__ qIdx, const int* __restrict__ aIdx,
    const float* __restrict__ emb,
    const float* __restrict__ smW, const float* __restrict__ ctxW,
    const float* __restrict__ attnW, const float* __restrict__ ctxfcW,
    const float* __restrict__ ctxfcb, const float* __restrict__ attnb,
    short* __restrict__ Ae1, short* __restrict__ Ae2,
    short* __restrict__ BTall, float* __restrict__ Wcat, float* __restrict__ bvec,
    float* __restrict__ cosb) {
  __shared__ float lds[5810];
  int bid = blockIdx.x, tid = threadIdx.x;
  int w = tid >> 6, lane = tid & 63;
  if (bid < 256) {
    // ---- cosine: block = (b, a-quarter of 15 rows) ----
    int b = bid >> 2, aq = bid & 3;
    float* s2  = lds;          // [15][305]
    float* s1b = lds + 4575;   // [4][305]
    float* naL = lds + 5795;   // [15]
    for (int r = w; r < 15; r += 4) {
      int tok = aIdx[b * ALn + aq * 15 + r];
      const float4* src = (const float4*)(emb + (size_t)tok * Dn);
      float ssq = 0.f;
      for (int i = lane; i < 76; i += 64) {
        float4 v = (i < 75) ? src[i] : make_float4(0.f, 0.f, 0.f, 0.f);
        ssq += v.x * v.x + v.y * v.y + v.z * v.z + v.w * v.w;
        *(float4*)&s2[r * 305 + i * 4] = v;
      }
      #pragma unroll
      for (int o = 32; o; o >>= 1) ssq += __shfl_down(ssq, o, 64);
      if (lane == 0) naL[r] = sqrtf(ssq);
    }
    __syncthreads();
    int ap = lane >> 2, h = lane & 3;
    for (int qi = 0; qi < 10; ++qi) {
      int qq = w * 10 + qi;
      int tok = qIdx[b * QLn + qq];
      const float4* src = (const float4*)(emb + (size_t)tok * Dn);
      float ssq = 0.f;
      for (int i = lane; i < 76; i += 64) {
        float4 v = (i < 75) ? src[i] : make_float4(0.f, 0.f, 0.f, 0.f);
        ssq += v.x * v.x + v.y * v.y + v.z * v.z + v.w * v.w;
        *(float4*)&s1b[w * 305 + i * 4] = v;
      }
      #pragma unroll
      for (int o = 32; o; o >>= 1) ssq += __shfl_down(ssq, o, 64);
      float nq2 = __shfl(ssq, 0, 64);
      __syncthreads();   // s1b visible within wave; uniform barrier across block
      float dot = 0.f;
      if (ap < 15) {
        const float* s2r = &s2[ap * 305 + h * 76];
        const float* s1r = &s1b[w * 305 + h * 76];
        #pragma unroll 4
        for (int k4 = 0; k4 < 19; ++k4) {
          float4 x = *(const float4*)&s1r[k4 * 4];
          float4 y = *(const float4*)&s2r[k4 * 4];
          dot += x.x * y.x + x.y * y.y + x.z * y.z + x.w * y.w;
        }
      }
      dot += __shfl_xor(dot, 1, 64);
      dot += __shfl_xor(dot, 2, 64);
      if (ap < 15 && h == 0) {
        float den = fmaxf(sqrtf(nq2) * naL[ap], 1e-6f);
        cosb[((size_t)b * QLn + qq) * ALn + aq * 15 + ap] = dot / den;
      }
    }
  } else if (bid < 1856) {
    // ---- gather: 4 rows per block, vectorized ----
    int row = (bid - 256) * 4 + w;
    const int* idxp; short* Ae; int r;
    if (row < 2560) { idxp = qIdx; Ae = Ae1; r = row; }
    else { idxp = aIdx; Ae = Ae2; r = row - 2560; }
    int tok = idxp[r];
    const float4* src = (const float4*)(emb + (size_t)tok * Dn);
    short* d = Ae + (size_t)r * KS;
    for (int i = lane; i < 80; i += 64) {
      float4 v = (i < 75) ? src[i] : make_float4(0.f, 0.f, 0.f, 0.f);
      short4 h4, l4;
      h4.x = f2bf(v.x); l4.x = f2bf(v.x - bf2f((unsigned short)h4.x));
      h4.y = f2bf(v.y); l4.y = f2bf(v.y - bf2f((unsigned short)h4.y));
      h4.z = f2bf(v.z); l4.z = f2bf(v.z - bf2f((unsigned short)h4.z));
      h4.w = f2bf(v.w); l4.w = f2bf(v.w - bf2f((unsigned short)h4.w));
      *(short4*)&d[i * 4] = h4;
      *(short4*)&d[320 + i * 4] = l4;
    }
  } else if (bid < 2056) {
    // ---- BT transpose: 64n x 64k tile, coalesced both sides ----
    int tb = bid - 1856;
    int kt = tb % 5, nt = tb / 5;
    int n0 = nt * 64;
    const float* src; int cb;
    if (n0 < 768)       { src = smW + (n0 >> 8) * 76800; cb = n0 & 255; }
    else if (n0 < 1024) { src = attnW + 65536;           cb = n0 - 768; }
    else if (n0 < 1792) { int m = n0 - 1024; src = smW + (m >> 8) * 76800; cb = m & 255; }
    else                { int m = n0 - 1792; src = ctxW + (m >> 8) * 76800; cb = m & 255; }
    float* tile = lds;   // [64][65]
    int nn = tid & 63;
    #pragma unroll
    for (int it = 0; it < 16; ++it) {
      int kl = it * 4 + w;
      int k = kt * 64 + kl;
      tile[kl * 65 + nn] = (k < 300) ? src[(size_t)k * 256 + cb + nn] : 0.f;
    }
    __syncthreads();
    #pragma unroll
    for (int it = 0; it < 16; ++it) {
      int nloc = it * 4 + w;
      int kl = tid & 63;
      float v = tile[kl * 65 + nloc];
      int n = n0 + nloc, k = kt * 64 + kl;
      short hi = f2bf(v), lo = f2bf(v - bf2f((unsigned short)hi));
      BTall[(size_t)n * KS + k] = hi;
      BTall[(size_t)n * KS + 320 + k] = lo;
    }
  } else {
    // ---- Wcat / bvec (4 independent FMA chains) ----
    int k = bid - 2056;            // 0..256
    float* rowv = lds;
    int j = tid;
    rowv[j] = (k < 256) ? ctxfcW[(size_t)k * 256 + j] : ctxfcb[j];
    __syncthreads();
    float a0 = 0.f, a1 = 0.f, a2 = 0.f, a3 = 0.f;
    for (int m = 0; m < 256; m += 4) {
      a0 += rowv[m]     * attnW[(size_t)m * 256 + j];
      a1 += rowv[m + 1] * attnW[(size_t)(m + 1) * 256 + j];
      a2 += rowv[m + 2] * attnW[(size_t)(m + 2) * 256 + j];
      a3 += rowv[m + 3] * attnW[(size_t)(m + 3) * 256 + j];
    }
    float acc = (a0 + a1) + (a2 + a3);
    if (k < 256) {
      Wcat[(size_t)k * 512 + j] = rowv[j];
      Wcat[(size_t)k * 512 + 256 + j] = acc;
    } else {
      bvec[j] = ctxfcb[j];
      bvec[256 + j] = acc + attnb[j];
    }
  }
}

// ============ split mega MFMA GEMM, 3-phase over [hi|lo] storage ============
__device__ __forceinline__ void gl2lds16(const short* g, short* l) {
  __builtin_amdgcn_global_load_lds(
      (const __attribute__((address_space(1))) unsigned int*)g,
      (__attribute__((address_space(3))) unsigned int*)l, 16, 0, 0);
}

__global__ __launch_bounds__(256) void k_mega(
    const short* __restrict__ Ae1, const short* __restrict__ Ae2,
    const short* __restrict__ BTall, float* __restrict__ ZQ, float* __restrict__ ZA) {
  __shared__ __align__(16) short As[128 * 32];
  __shared__ __align__(16) short Bs[128 * 32];
  int tid = threadIdx.x;
  int wid = tid >> 6, lane = tid & 63;
  int l15 = lane & 15, l4 = lane >> 4;
  int bid = blockIdx.x;
  int lin = (bid & 7) * 65 + (bid >> 3);   // bijective XCD swizzle, 520 = 8 x 65
  const short *A, *BT; float* C; int bx, by, ldc;
  if (lin < 160) {            // Q job: 20 x 8 tiles
    int chunk = lin >> 4, ww = lin & 15;
    by = ww >> 1; bx = chunk * 2 + (ww & 1);
    A = Ae1; BT = BTall; C = ZQ; ldc = NQ;
  } else {                    // A job: 30 x 12 tiles
    int l2 = lin - 160;
    int chunk = l2 / 24, ww = l2 % 24;
    by = ww >> 1; bx = chunk * 2 + (ww & 1);
    A = Ae2; BT = BTall + (size_t)1024 * KS; C = ZA; ldc = NA;
  }
  int rowBase = bx * 128, colBase = by * 128;
  int mw = wid * 32;

  f32x4 acc[2][8];
  #pragma unroll
  for (int i = 0; i < 2; ++i)
    #pragma unroll
    for (int j = 0; j < 8; ++j) acc[i][j] = (f32x4){0.f, 0.f, 0.f, 0.f};

  int rowA0 = mw + l15, rowA1 = mw + 16 + l15;
  int sA0 = (l4 ^ ((rowA0 >> 1) & 3)) << 3;
  int sA1 = (l4 ^ ((rowA1 >> 1) & 3)) << 3;

  #pragma unroll 1
  for (int g = 0; g < 3; ++g) {
    int aoff = (g == 1) ? 320 : 0;
    int boff = (g == 2) ? 320 : 0;
    #pragma unroll 1
    for (int ks = 0; ks < 10; ++ks) {
      int ka0 = aoff + ks * 32, kb0 = boff + ks * 32;
      #pragma unroll
      for (int j = 0; j < 2; ++j) {
        int idx = tid + j * 256;          // chunk id 0..511
        int r = idx >> 2, s = idx & 3;
        int sl = s ^ ((r >> 1) & 3);      // inverse-swizzled source slot
        int chunkStart = j * 256 + wid * 64;   // wave-uniform LDS base
        gl2lds16(A + (size_t)(rowBase + r) * KS + ka0 + (sl << 3), &As[chunkStart * 8]);
        gl2lds16(BT + (size_t)(colBase + r) * KS + kb0 + (sl << 3), &Bs[chunkStart * 8]);
      }
      __syncthreads();
      bf16x8 a0 = *reinterpret_cast<const bf16x8*>(&As[rowA0 * 32 + sA0]);
      bf16x8 a1 = *reinterpret_cast<const bf16x8*>(&As[rowA1 * 32 + sA1]);
      #pragma unroll
      for (int nj = 0; nj < 8; ++nj) {
        int rb = nj * 16 + l15;
        bf16x8 bf = *reinterpret_cast<const bf16x8*>(&Bs[rb * 32 + ((l4 ^ ((rb >> 1) & 3)) << 3)]);
        acc[0][nj] = __builtin_amdgcn_mfma_f32_16x16x32_bf16(a0, bf, acc[0][nj], 0, 0, 0);
        acc[1][nj] = __builtin_amdgcn_mfma_f32_16x16x32_bf16(a1, bf, acc[1][nj], 0, 0, 0);
      }
      __syncthreads();
    }
  }
  #pragma unroll
  for (int mi = 0; mi < 2; ++mi) {
    int row0 = rowBase + mw + mi * 16 + l4 * 4;
    #pragma unroll
    for (int nj = 0; nj < 8; ++nj) {
      int col = colBase + nj * 16 + l15;
      #pragma unroll
      for (int r = 0; r < 4; ++r)
        C[(size_t)(row0 + r) * ldc + col] = acc[mi][nj][r];
    }
  }
}

// ============ fused: sm pool t-split (256) | ctx cos-gated pool (512) ============
__global__ void k_poolctx(const float* __restrict__ ZQ, const float* __restrict__ ZA,
                          const float* __restrict__ convb, const float* __restrict__ cosb,
                          const float* __restrict__ ctxb,
                          float* __restrict__ pooled_part, float* __restrict__ pctx_part) {
  __shared__ float cl[10][ALn];
  int bid = blockIdx.x, tid = threadIdx.x;
  if (bid < 256) {
    // ---- sm conv 3-tap + relu + maxpool half ----
    int blk = bid & 127, half = bid >> 7;
    int c = tid;
    const float* base; int P, ld;
    if (blk < Bn) { base = ZQ + (size_t)blk * QLn * NQ; P = QLn - 2; ld = NQ; }
    else          { base = ZA + (size_t)(blk - Bn) * ALn * NA; P = ALn - 2; ld = NA; }
    int t0 = half * (P >> 1), t1 = (half ? P : (P >> 1));
    float bias = convb[c];
    float m = 0.f;
    #pragma unroll 4
    for (int t = t0; t < t1; ++t) {
      float v = bias + base[t * ld + c] + base[(t + 1) * ld + 256 + c]
                     + base[(t + 2) * ld + 512 + c];
      m = fmaxf(m, v);
    }
    pooled_part[((size_t)half * 128 + blk) * 256 + c] = m;
  } else {
    // ---- ctx conv: (qg, t-half) x b ----
    int bid2 = bid - 256;
    int b = bid2 & 63, sub = bid2 >> 6;
    int qg = sub >> 1, th = sub & 1;
    int c = tid;
    for (int i = tid; i < 10 * ALn; i += 256) {
      int qq = i / ALn, tt = i % ALn;
      cl[qq][tt] = cosb[((size_t)b * QLn + qg * 10 + qq) * ALn + tt];
    }
    __syncthreads();
    const float* base = ZA + (size_t)b * ALn * NA + 768;
    float bias = ctxb[c];
    float m[10];
    #pragma unroll
    for (int qq = 0; qq < 10; ++qq) m[qq] = 0.f;
    int t0 = th * 29;
    #pragma unroll 2
    for (int t = t0; t < t0 + 29; ++t) {
      float v0 = base[t * NA + c];
      float v1 = base[(t + 1) * NA + 256 + c];
      float v2 = base[(t + 2) * NA + 512 + c];
      #pragma unroll
      for (int qq = 0; qq < 10; ++qq) {
        float v = bias + cl[qq][t] * v0 + cl[qq][t + 1] * v1 + cl[qq][t + 2] * v2;
        m[qq] = fmaxf(m[qq], v);
      }
    }
    #pragma unroll
    for (int qq = 0; qq < 10; ++qq)
      pctx_part[((size_t)th * 2560 + (size_t)b * QLn + qg * 10 + qq) * 256 + c] = m[qq];
  }
}

// ============ fused: fc (32 blocks) | ctx-fc+attn-MLP+score (320 blocks) ============
__global__ __launch_bounds__(256) void k_fcattn(
    const float* __restrict__ pooled_part, const float* __restrict__ smfcW,
    const float* __restrict__ smfcb,
    const float* __restrict__ pctx_part, const float* __restrict__ Wcat,
    const float* __restrict__ bvec, const float* __restrict__ ZQ,
    const float* __restrict__ probW,
    float* __restrict__ feat_comb, float* __restrict__ feat, float* __restrict__ score) {
  __shared__ float lds[10304];
  int bid = blockIdx.x, j = threadIdx.x;
  if (bid < 32) {
    float* xin = lds;            // [256][4]
    float* wt  = lds + 1024;     // [32][256]
    int r0 = bid * 4;
    #pragma unroll
    for (int rr = 0; rr < 4; ++rr)
      xin[j * 4 + rr] = fmaxf(pooled_part[(size_t)(r0 + rr) * 256 + j],
                              pooled_part[(size_t)(128 + r0 + rr) * 256 + j]);
    float acc[4];
    #pragma unroll
    for (int rr = 0; rr < 4; ++rr) acc[rr] = smfcb[j];
    for (int ph = 0; ph < 8; ++ph) {
      const float4* src = (const float4*)(smfcW + (size_t)ph * 32 * 256);
      float4* dst = (float4*)wt;
      #pragma unroll
      for (int i = 0; i < 8; ++i) dst[i * 256 + j] = src[i * 256 + j];
      __syncthreads();
      #pragma unroll
      for (int kk = 0; kk < 32; ++kk) {
        float4 x = *reinterpret_cast<const float4*>(&xin[(ph * 32 + kk) * 4]);
        float wv = wt[kk * 256 + j];
        acc[0] += x.x * wv; acc[1] += x.y * wv; acc[2] += x.z * wv; acc[3] += x.w * wv;
      }
      __syncthreads();
    }
    #pragma unroll
    for (int rr = 0; rr < 4; ++rr) {
      int row = r0 + rr;
      feat_comb[(size_t)(row & 63) * 768 + ((row >> 6) * 256) + j] = acc[rr];
    }
  } else {
    float* xin  = lds;           // [256][8]
    float* wt   = lds + 2048;    // [16][512]
    float* sred = lds + 10240;   // [8][4]
    int r0 = (bid - 32) * 8;
    #pragma unroll
    for (int rr = 0; rr < 8; ++rr)
      xin[j * 8 + rr] = fmaxf(pctx_part[(size_t)(r0 + rr) * 256 + j],
                              pctx_part[(size_t)(2560 + r0 + rr) * 256 + j]);
    float hf[8], hh[8];
    float bf0 = bvec[j], bh0 = bvec[256 + j];
    #pragma unroll
    for (int rr = 0; rr < 8; ++rr) {
      hf[rr] = bf0;
      hh[rr] = bh0 + ZQ[(size_t)(r0 + rr) * NQ + 768 + j];
    }
    for (int ph = 0; ph < 16; ++ph) {
      const float4* src = (const float4*)(Wcat + (size_t)ph * 16 * 512);
      float4* dst = (float4*)wt;
      #pragma unroll
      for (int i = 0; i < 8; ++i) dst[i * 256 + j] = src[i * 256 + j];
      __syncthreads();
      #pragma unroll
      for (int kk = 0; kk < 16; ++kk) {
        int k = ph * 16 + kk;
        float4 x0 = *reinterpret_cast<const float4*>(&xin[k * 8]);
        float4 x1 = *reinterpret_cast<const float4*>(&xin[k * 8 + 4]);
        float w0 = wt[kk * 512 + j], w1 = wt[kk * 512 + 256 + j];
        hf[0] += x0.x * w0; hf[1] += x0.y * w0; hf[2] += x0.z * w0; hf[3] += x0.w * w0;
        hf[4] += x1.x * w0; hf[5] += x1.y * w0; hf[6] += x1.z * w0; hf[7] += x1.w * w0;
        hh[0] += x0.x * w1; hh[1] += x0.y * w1; hh[2] += x0.z * w1; hh[3] += x0.w * w1;
        hh[4] += x1.x * w1; hh[5] += x1.y * w1; hh[6] += x1.z * w1; hh[7] += x1.w * w1;
      }
      __syncthreads();
    }
    #pragma unroll
    for (int rr = 0; rr < 8; ++rr)
      feat[(size_t)(r0 + rr) * 256 + j] = hf[rr];
    float pw = probW[j];
    int lane = j & 63, wv = j >> 6;
    #pragma unroll
    for (int rr = 0; rr < 8; ++rr) {
      float s = tanhf(hh[rr]) * pw;
      #pragma unroll
      for (int off = 32; off; off >>= 1) s += __shfl_down(s, off, 64);
      if (lane == 0) sred[rr * 4 + wv] = s;
    }
    __syncthreads();
    if (j < 8) score[r0 + j] = sred[j * 4] + sred[j * 4 + 1] + sred[j * 4 + 2] + sred[j * 4 + 3];
  }
}

// ============ softmax over q + weighted feat pool -> feat_comb[:,512:768] ============
__global__ void k_attnpool(const float* __restrict__ score, const float* __restrict__ feat,
                           float* __restrict__ feat_comb) {
  int b = blockIdx.x;
  int tid = threadIdx.x;
  __shared__ float p[QLn];
  __shared__ float inv;
  if (tid < 64) {
    float sc = (tid < QLn) ? score[b * QLn + tid] : -1e30f;
    float mx = sc;
    #pragma unroll
    for (int off = 32; off; off >>= 1) mx = fmaxf(mx, __shfl_xor(mx, off, 64));
    float e = (tid < QLn) ? expf(sc - mx) : 0.f;
    if (tid < QLn) p[tid] = e;
    float den = e;
    #pragma unroll
    for (int off = 32; off; off >>= 1) den += __shfl_xor(den, off, 64);
    if (tid == 0) inv = 1.f / den;
  }
  __syncthreads();
  float acc = 0.f;
  for (int qq = 0; qq < QLn; ++qq)
    acc += p[qq] * feat[((size_t)b * QLn + qq) * 256 + tid];
  feat_comb[(size_t)b * 768 + 512 + tid] = acc * inv;
}

// ============ fused W1 + bias + BatchNorm + tanh ============
__global__ __launch_bounds__(256) void k_w1bn(
    const float* __restrict__ feat_comb, const float* __restrict__ W1,
    const float* __restrict__ b1, const float* __restrict__ gamma,
    const float* __restrict__ beta, float* __restrict__ feat_out) {
  int j0 = blockIdx.x * 8;
  int tid = threadIdx.x;
  __shared__ float wl[768][12];
  __shared__ float hb[64][8];
  for (int it = 0; it < 24; ++it) {
    int idx = tid + it * 256;
    int k = idx >> 3, jj = idx & 7;
    wl[k][jj] = W1[(size_t)k * 512 + j0 + jj];
  }
  __syncthreads();
  int n = tid >> 2, p = tid & 3;
  float acc[8] = {0.f, 0.f, 0.f, 0.f, 0.f, 0.f, 0.f, 0.f};
  const float* frow = feat_comb + (size_t)n * 768 + p;
  for (int i = 0; i < 192; ++i) {
    float v = frow[i * 4];
    int k = p + i * 4;
    float4 w0 = *reinterpret_cast<const float4*>(&wl[k][0]);
    float4 w1v = *reinterpret_cast<const float4*>(&wl[k][4]);
    acc[0] += v * w0.x; acc[1] += v * w0.y; acc[2] += v * w0.z; acc[3] += v * w0.w;
    acc[4] += v * w1v.x; acc[5] += v * w1v.y; acc[6] += v * w1v.z; acc[7] += v * w1v.w;
  }
  #pragma unroll
  for (int jj = 0; jj < 8; ++jj) {
    acc[jj] += __shfl_xor(acc[jj], 1, 64);
    acc[jj] += __shfl_xor(acc[jj], 2, 64);
  }
  if (p == 0) {
    #pragma unroll
    for (int jj = 0; jj < 8; ++jj) hb[n][jj] = acc[jj] + b1[j0 + jj];
  }
  __syncthreads();
  if (tid < 64) {
    #pragma unroll
    for (int jj = 0; jj < 8; ++jj) {
      float v = hb[tid][jj];
      float s = v;
      #pragma unroll
      for (int off = 32; off; off >>= 1) s += __shfl_xor(s, off, 64);
      float mu = s * (1.f / 64.f);
      float d = v - mu;
      float q2 = d * d;
      #pragma unroll
      for (int off = 32; off; off >>= 1) q2 += __shfl_xor(q2, off, 64);
      float var = q2 * (1.f / 64.f);
      feat_out[(size_t)tid * 512 + j0 + jj] =
          tanhf(d * rsqrtf(var + 1e-5f) * gamma[j0 + jj] + beta[j0 + jj]);
    }
  }
}

// ============ head: 2-class logits + log_softmax ============
__global__ void k_head(const float* __restrict__ feat_out, const float* __restrict__ W2,
                       const float* __restrict__ b2, float* __restrict__ preds) {
  int n = blockIdx.x;
  int tid = threadIdx.x;
  float a0 = 0.f, a1 = 0.f;
  for (int j = tid; j < 512; j += 64) {
    float f = feat_out[(size_t)n * 512 + j];
    a0 += f * W2[j * 2 + 0];
    a1 += f * W2[j * 2 + 1];
  }
  #pragma unroll
  for (int off = 32; off; off >>= 1) {
    a0 += __shfl_down(a0, off, 64);
    a1 += __shfl_down(a1, off, 64);
  }
  if (tid == 0) {
    float l0 = a0 + b2[0], l1 = a1 + b2[1];
    float mx = fmaxf(l0, l1);
    float lse = mx + logf(expf(l0 - mx) + expf(l1 - mx));
    preds[n * 2 + 0] = l0 - lse;
    preds[n * 2 + 1] = l1 - lse;
  }
}

extern "C" void kernel_launch(void* const* d_in, const int* in_sizes, int n_in,
                              void* d_out, int out_size, void* d_ws, size_t ws_size,
                              hipStream_t stream) {
  (void)in_sizes; (void)n_in; (void)out_size; (void)ws_size;
  const int*   question  = (const int*)d_in[0];
  const int*   answer    = (const int*)d_in[1];
  const float* embedding = (const float*)d_in[3];
  const float* sm_convW  = (const float*)d_in[4];
  const float* sm_convb  = (const float*)d_in[5];
  const float* sm_fcW    = (const float*)d_in[6];
  const float* sm_fcb    = (const float*)d_in[7];
  const float* ctx_convW = (const float*)d_in[8];
  const float* ctx_convb = (const float*)d_in[9];
  const float* ctx_fcW   = (const float*)d_in[10];
  const float* ctx_fcb   = (const float*)d_in[11];
  const float* attnW     = (const float*)d_in[12];
  const float* attnb     = (const float*)d_in[13];
  const float* probW     = (const float*)d_in[14];
  const float* W1        = (const float*)d_in[15];
  const float* b1        = (const float*)d_in[16];
  const float* gamma     = (const float*)d_in[17];
  const float* beta      = (const float*)d_in[18];
  const float* W2        = (const float*)d_in[19];
  const float* b2        = (const float*)d_in[20];

  float* out = (float*)d_out;   // [0:128) preds, [128:) feat_out 64x512
  char* base = (char*)d_ws;
  size_t off = 0;
  auto alloc = [&](size_t bytes) { char* p = base + off; off += (bytes + 255) & ~(size_t)255; return p; };

  short* Ae1   = (short*)alloc(2560ull * KS * 2);      // 3.28 MB
  short* Ae2   = (short*)alloc(3840ull * KS * 2);      // 4.92 MB
  short* BTall = (short*)alloc(2560ull * KS * 2);      // 3.28 MB; dead after k_mega
  float* ZQ    = (float*)alloc(2560ull * NQ * 4);      // 10.5 MB
  float* ZA    = (float*)alloc(3840ull * NA * 4);      // 23.6 MB
  float* cosb  = (float*)alloc(2560ull * ALn * 4);     // 614 KB (written by k_prep)
  float* Wcat  = (float*)alloc(256ull * 512 * 4);
  float* bvec  = (float*)alloc(512 * 4);
  float* pctx_part = (float*)alloc(2ull * 2560 * 256 * 4);
  float* feat      = (float*)alloc(2560ull * 256 * 4);
  float* feat_comb = (float*)alloc(64ull * 768 * 4);
  float* score     = (float*)alloc(2560 * 4);
  float* pooled_part = (float*)BTall;                  // overlay (dead after k_mega)

  // 1. prep: cos | gather | BT-transpose | Wcat (2313 blocks)
  k_prep<<<2313, 256, 0, stream>>>(question, answer, embedding, sm_convW, ctx_convW,
                                   attnW, ctx_fcW, ctx_fcb, attnb,
                                   Ae1, Ae2, BTall, Wcat, bvec, cosb);
  // 2. split mega GEMM (520 blocks)
  k_mega<<<520, 256, 0, stream>>>(Ae1, Ae2, BTall, ZQ, ZA);
  // 3. sm pool | ctx pool (768 blocks)
  k_poolctx<<<768, 256, 0, stream>>>(ZQ, ZA, sm_convb, cosb, ctx_convb,
                                     pooled_part, pctx_part);
  // 4. fc | ctx-fc+attn+score (352 blocks)
  k_fcattn<<<352, 256, 0, stream>>>(pooled_part, sm_fcW, sm_fcb,
                                    pctx_part, Wcat, bvec, ZQ, probW,
                                    feat_comb, feat, score);
  // 5. softmax-pool -> feat_comb cols 512..767
  k_attnpool<<<Bn, 256, 0, stream>>>(score, feat, feat_comb);
  // 6. fused W1 + BN + tanh -> feat_out
  k_w1bn<<<64, 256, 0, stream>>>(feat_comb, W1, b1, gamma, beta, out + 128);
  // 7. head -> preds
  k_head<<<Bn, 64, 0, stream>>>(out + 128, W2, b2, out);
}

// Round 8
// 113.646 us; speedup vs baseline: 4.6606x; 1.3847x over previous
//
#include <hip/hip_runtime.h>
#include <math.h>

#define Bn 64
#define QLn 40
#define ALn 60
#define Dn 300
#define KS 640       /* stored row width: [hi(320) | lo(320)] */
#define NQ 1024      /* Q job cols: 768 sm-conv | 256 attnW2 */
#define NA 1536      /* A job cols: 768 sm-conv | 768 ctx-conv */

typedef __attribute__((ext_vector_type(8))) short bf16x8;
typedef __attribute__((ext_vector_type(4))) float f32x4;

__device__ __forceinline__ float bf2f(unsigned short s) {
  return __uint_as_float(((unsigned)s) << 16);
}
__device__ __forceinline__ short f2bf(float f) {
  unsigned u = __float_as_uint(f);
  unsigned r = (u + 0x7FFFu + ((u >> 16) & 1u)) >> 16;
  return (short)r;
}

// ============ fused prep ============
// bid [0,1600): gather -> split-bf16 [hi|lo] + row norms
// bid [1600,1800): BT transpose (coalesced, LDS tile)
// bid [1800,2057): Wcat = [ctxfcW | ctxfcW@attnW0] + bvec
__global__ __launch_bounds__(256) void k_prep(
    const int* __restrict__ qIdx, const int* __restrict__ aIdx,
    const float* __restrict__ emb,
    const float* __restrict__ smW, const float* __restrict__ ctxW,
    const float* __restrict__ attnW, const float* __restrict__ ctxfcW,
    const float* __restrict__ ctxfcb, const float* __restrict__ attnb,
    short* __restrict__ Ae1, short* __restrict__ Ae2,
    float* __restrict__ nq, float* __restrict__ na,
    short* __restrict__ BTall, float* __restrict__ Wcat, float* __restrict__ bvec) {
  __shared__ float lds[4160];
  int bid = blockIdx.x, tid = threadIdx.x;
  int w = tid >> 6, lane = tid & 63;
  if (bid < 1600) {
    // ---- gather: 4 rows per block (1 per wave), vectorized, with norms ----
    int row = bid * 4 + w;
    const int* idxp; short* Ae; float* nrm; int r;
    if (row < 2560) { idxp = qIdx; Ae = Ae1; nrm = nq; r = row; }
    else { idxp = aIdx; Ae = Ae2; nrm = na; r = row - 2560; }
    int tok = idxp[r];
    const float4* src = (const float4*)(emb + (size_t)tok * Dn);
    short* d = Ae + (size_t)r * KS;
    float ssq = 0.f;
    for (int i = lane; i < 80; i += 64) {
      float4 v = (i < 75) ? src[i] : make_float4(0.f, 0.f, 0.f, 0.f);
      ssq += v.x * v.x + v.y * v.y + v.z * v.z + v.w * v.w;
      short4 h4, l4v;
      h4.x = f2bf(v.x); l4v.x = f2bf(v.x - bf2f((unsigned short)h4.x));
      h4.y = f2bf(v.y); l4v.y = f2bf(v.y - bf2f((unsigned short)h4.y));
      h4.z = f2bf(v.z); l4v.z = f2bf(v.z - bf2f((unsigned short)h4.z));
      h4.w = f2bf(v.w); l4v.w = f2bf(v.w - bf2f((unsigned short)h4.w));
      *(short4*)&d[i * 4] = h4;
      *(short4*)&d[320 + i * 4] = l4v;
    }
    #pragma unroll
    for (int o = 32; o; o >>= 1) ssq += __shfl_down(ssq, o, 64);
    if (lane == 0) nrm[r] = sqrtf(ssq);
  } else if (bid < 1800) {
    // ---- BT transpose: 64n x 64k tile, coalesced both sides ----
    int tb = bid - 1600;
    int kt = tb % 5, nt = tb / 5;
    int n0 = nt * 64;
    const float* src; int cb;
    if (n0 < 768)       { src = smW + (n0 >> 8) * 76800; cb = n0 & 255; }
    else if (n0 < 1024) { src = attnW + 65536;           cb = n0 - 768; }
    else if (n0 < 1792) { int m = n0 - 1024; src = smW + (m >> 8) * 76800; cb = m & 255; }
    else                { int m = n0 - 1792; src = ctxW + (m >> 8) * 76800; cb = m & 255; }
    float* tile = lds;   // [64][65]
    int nn = tid & 63;
    #pragma unroll
    for (int it = 0; it < 16; ++it) {
      int kl = it * 4 + w;
      int k = kt * 64 + kl;
      tile[kl * 65 + nn] = (k < 300) ? src[(size_t)k * 256 + cb + nn] : 0.f;
    }
    __syncthreads();
    #pragma unroll
    for (int it = 0; it < 16; ++it) {
      int nloc = it * 4 + w;
      int kl = tid & 63;
      float v = tile[kl * 65 + nloc];
      int n = n0 + nloc, k = kt * 64 + kl;
      short hi = f2bf(v), lo = f2bf(v - bf2f((unsigned short)hi));
      BTall[(size_t)n * KS + k] = hi;
      BTall[(size_t)n * KS + 320 + k] = lo;
    }
  } else {
    // ---- Wcat / bvec (4 independent FMA chains) ----
    int k = bid - 1800;            // 0..256
    float* rowv = lds;
    int j = tid;
    rowv[j] = (k < 256) ? ctxfcW[(size_t)k * 256 + j] : ctxfcb[j];
    __syncthreads();
    float a0 = 0.f, a1 = 0.f, a2 = 0.f, a3 = 0.f;
    for (int m = 0; m < 256; m += 4) {
      a0 += rowv[m]     * attnW[(size_t)m * 256 + j];
      a1 += rowv[m + 1] * attnW[(size_t)(m + 1) * 256 + j];
      a2 += rowv[m + 2] * attnW[(size_t)(m + 2) * 256 + j];
      a3 += rowv[m + 3] * attnW[(size_t)(m + 3) * 256 + j];
    }
    float acc = (a0 + a1) + (a2 + a3);
    if (k < 256) {
      Wcat[(size_t)k * 512 + j] = rowv[j];
      Wcat[(size_t)k * 512 + 256 + j] = acc;
    } else {
      bvec[j] = ctxfcb[j];
      bvec[256 + j] = acc + attnb[j];
    }
  }
}

// ============ split mega MFMA GEMM + MFMA cosine, 3-phase over [hi|lo] ============
__device__ __forceinline__ void gl2lds16(const short* g, short* l) {
  __builtin_amdgcn_global_load_lds(
      (const __attribute__((address_space(1))) unsigned int*)g,
      (__attribute__((address_space(3))) unsigned int*)l, 16, 0, 0);
}

__global__ __launch_bounds__(256) void k_mega(
    const short* __restrict__ Ae1, const short* __restrict__ Ae2,
    const short* __restrict__ BTall, float* __restrict__ ZQ, float* __restrict__ ZA,
    const float* __restrict__ nq, const float* __restrict__ na,
    float* __restrict__ cosb) {
  __shared__ __align__(16) short As[128 * 32];
  __shared__ __align__(16) short Bs[128 * 32];
  int tid = threadIdx.x;
  int wid = tid >> 6, lane = tid & 63;
  int l15 = lane & 15, l4 = lane >> 4;
  int bid = blockIdx.x;
  int lin = (bid & 7) * 73 + (bid >> 3);   // bijective XCD swizzle, 584 = 8 x 73

  if (lin < 520) {
    // ================= GEMM jobs =================
    const short *A, *BT; float* C; int bx, by, ldc;
    if (lin < 160) {            // Q job: 20 x 8 tiles
      int chunk = lin >> 4, ww = lin & 15;
      by = ww >> 1; bx = chunk * 2 + (ww & 1);
      A = Ae1; BT = BTall; C = ZQ; ldc = NQ;
    } else {                    // A job: 30 x 12 tiles
      int l2 = lin - 160;
      int chunk = l2 / 24, ww = l2 % 24;
      by = ww >> 1; bx = chunk * 2 + (ww & 1);
      A = Ae2; BT = BTall + (size_t)1024 * KS; C = ZA; ldc = NA;
    }
    int rowBase = bx * 128, colBase = by * 128;
    int mw = wid * 32;

    f32x4 acc[2][8];
    #pragma unroll
    for (int i = 0; i < 2; ++i)
      #pragma unroll
      for (int j = 0; j < 8; ++j) acc[i][j] = (f32x4){0.f, 0.f, 0.f, 0.f};

    int rowA0 = mw + l15, rowA1 = mw + 16 + l15;
    int sA0 = (l4 ^ ((rowA0 >> 1) & 3)) << 3;
    int sA1 = (l4 ^ ((rowA1 >> 1) & 3)) << 3;

    #pragma unroll 1
    for (int g = 0; g < 3; ++g) {
      int aoff = (g == 1) ? 320 : 0;
      int boff = (g == 2) ? 320 : 0;
      #pragma unroll 1
      for (int ks = 0; ks < 10; ++ks) {
        int ka0 = aoff + ks * 32, kb0 = boff + ks * 32;
        #pragma unroll
        for (int j = 0; j < 2; ++j) {
          int idx = tid + j * 256;          // chunk id 0..511
          int r = idx >> 2, s = idx & 3;
          int sl = s ^ ((r >> 1) & 3);      // inverse-swizzled source slot
          int chunkStart = j * 256 + wid * 64;   // wave-uniform LDS base
          gl2lds16(A + (size_t)(rowBase + r) * KS + ka0 + (sl << 3), &As[chunkStart * 8]);
          gl2lds16(BT + (size_t)(colBase + r) * KS + kb0 + (sl << 3), &Bs[chunkStart * 8]);
        }
        __syncthreads();
        bf16x8 a0 = *reinterpret_cast<const bf16x8*>(&As[rowA0 * 32 + sA0]);
        bf16x8 a1 = *reinterpret_cast<const bf16x8*>(&As[rowA1 * 32 + sA1]);
        #pragma unroll
        for (int nj = 0; nj < 8; ++nj) {
          int rb = nj * 16 + l15;
          bf16x8 bf = *reinterpret_cast<const bf16x8*>(&Bs[rb * 32 + ((l4 ^ ((rb >> 1) & 3)) << 3)]);
          acc[0][nj] = __builtin_amdgcn_mfma_f32_16x16x32_bf16(a0, bf, acc[0][nj], 0, 0, 0);
          acc[1][nj] = __builtin_amdgcn_mfma_f32_16x16x32_bf16(a1, bf, acc[1][nj], 0, 0, 0);
        }
        __syncthreads();
      }
    }
    #pragma unroll
    for (int mi = 0; mi < 2; ++mi) {
      int row0 = rowBase + mw + mi * 16 + l4 * 4;
      #pragma unroll
      for (int nj = 0; nj < 8; ++nj) {
        int col = colBase + nj * 16 + l15;
        #pragma unroll
        for (int r = 0; r < 4; ++r)
          C[(size_t)(row0 + r) * ldc + col] = acc[mi][nj][r];
      }
    }
  } else {
    // ================= cosine job: per-b 64x64 MFMA tile =================
    int b = lin - 520;
    int rowBase = b * 40, colBase = b * 60;
    f32x4 cacc[4];
    #pragma unroll
    for (int nj = 0; nj < 4; ++nj) cacc[nj] = (f32x4){0.f, 0.f, 0.f, 0.f};
    int rowA = (wid << 4) + l15;
    int sA = (l4 ^ ((rowA >> 1) & 3)) << 3;

    #pragma unroll 1
    for (int g = 0; g < 3; ++g) {
      int aoff = (g == 1) ? 320 : 0;
      int boff = (g == 2) ? 320 : 0;
      #pragma unroll 1
      for (int ks = 0; ks < 10; ++ks) {
        int ka0 = aoff + ks * 32, kb0 = boff + ks * 32;
        int r = tid >> 2, s = tid & 3;
        int sl = s ^ ((r >> 1) & 3);
        int chunkStart = wid * 64;            // 256 chunks: lane writes chunk tid
        int gr = rowBase + r; if (gr > 2559) gr = 2559;
        int gc = colBase + r; if (gc > 3839) gc = 3839;
        gl2lds16(Ae1 + (size_t)gr * KS + ka0 + (sl << 3), &As[chunkStart * 8]);
        gl2lds16(Ae2 + (size_t)gc * KS + kb0 + (sl << 3), &Bs[chunkStart * 8]);
        __syncthreads();
        bf16x8 a0 = *reinterpret_cast<const bf16x8*>(&As[rowA * 32 + sA]);
        #pragma unroll
        for (int nj = 0; nj < 4; ++nj) {
          int rb = (nj << 4) + l15;
          bf16x8 bf = *reinterpret_cast<const bf16x8*>(&Bs[rb * 32 + ((l4 ^ ((rb >> 1) & 3)) << 3)]);
          cacc[nj] = __builtin_amdgcn_mfma_f32_16x16x32_bf16(a0, bf, cacc[nj], 0, 0, 0);
        }
        __syncthreads();
      }
    }
    int q0 = (wid << 4) + l4 * 4;
    #pragma unroll
    for (int nj = 0; nj < 4; ++nj) {
      int a = (nj << 4) + l15;
      if (a >= ALn) continue;
      float nav = na[colBase + a];
      #pragma unroll
      for (int r = 0; r < 4; ++r) {
        int qq = q0 + r;
        if (qq < QLn) {
          float den = fmaxf(nq[rowBase + qq] * nav, 1e-6f);
          cosb[(size_t)(rowBase + qq) * ALn + a] = cacc[nj][r] / den;
        }
      }
    }
  }
}

// ============ fused: sm pool t-split (256) | ctx cos-gated pool (512) ============
__global__ void k_poolctx(const float* __restrict__ ZQ, const float* __restrict__ ZA,
                          const float* __restrict__ convb, const float* __restrict__ cosb,
                          const float* __restrict__ ctxb,
                          float* __restrict__ pooled_part, float* __restrict__ pctx_part) {
  __shared__ float cl[10][ALn];
  int bid = blockIdx.x, tid = threadIdx.x;
  if (bid < 256) {
    int blk = bid & 127, half = bid >> 7;
    int c = tid;
    const float* base; int P, ld;
    if (blk < Bn) { base = ZQ + (size_t)blk * QLn * NQ; P = QLn - 2; ld = NQ; }
    else          { base = ZA + (size_t)(blk - Bn) * ALn * NA; P = ALn - 2; ld = NA; }
    int t0 = half * (P >> 1), t1 = (half ? P : (P >> 1));
    float bias = convb[c];
    float m = 0.f;
    #pragma unroll 4
    for (int t = t0; t < t1; ++t) {
      float v = bias + base[t * ld + c] + base[(t + 1) * ld + 256 + c]
                     + base[(t + 2) * ld + 512 + c];
      m = fmaxf(m, v);
    }
    pooled_part[((size_t)half * 128 + blk) * 256 + c] = m;
  } else {
    int bid2 = bid - 256;
    int b = bid2 & 63, sub = bid2 >> 6;
    int qg = sub >> 1, th = sub & 1;
    int c = tid;
    for (int i = tid; i < 10 * ALn; i += 256) {
      int qq = i / ALn, tt = i % ALn;
      cl[qq][tt] = cosb[((size_t)b * QLn + qg * 10 + qq) * ALn + tt];
    }
    __syncthreads();
    const float* base = ZA + (size_t)b * ALn * NA + 768;
    float bias = ctxb[c];
    float m[10];
    #pragma unroll
    for (int qq = 0; qq < 10; ++qq) m[qq] = 0.f;
    int t0 = th * 29;
    #pragma unroll 2
    for (int t = t0; t < t0 + 29; ++t) {
      float v0 = base[t * NA + c];
      float v1 = base[(t + 1) * NA + 256 + c];
      float v2 = base[(t + 2) * NA + 512 + c];
      #pragma unroll
      for (int qq = 0; qq < 10; ++qq) {
        float v = bias + cl[qq][t] * v0 + cl[qq][t + 1] * v1 + cl[qq][t + 2] * v2;
        m[qq] = fmaxf(m[qq], v);
      }
    }
    #pragma unroll
    for (int qq = 0; qq < 10; ++qq)
      pctx_part[((size_t)th * 2560 + (size_t)b * QLn + qg * 10 + qq) * 256 + c] = m[qq];
  }
}

// ============ fused: fc (32 blocks) | ctx-fc+attn-MLP+score (320 blocks) ============
__global__ __launch_bounds__(256) void k_fcattn(
    const float* __restrict__ pooled_part, const float* __restrict__ smfcW,
    const float* __restrict__ smfcb,
    const float* __restrict__ pctx_part, const float* __restrict__ Wcat,
    const float* __restrict__ bvec, const float* __restrict__ ZQ,
    const float* __restrict__ probW,
    float* __restrict__ feat_comb, float* __restrict__ feat, float* __restrict__ score) {
  __shared__ float lds[10304];
  int bid = blockIdx.x, j = threadIdx.x;
  if (bid < 32) {
    float* xin = lds;            // [256][4]
    float* wt  = lds + 1024;     // [32][256]
    int r0 = bid * 4;
    #pragma unroll
    for (int rr = 0; rr < 4; ++rr)
      xin[j * 4 + rr] = fmaxf(pooled_part[(size_t)(r0 + rr) * 256 + j],
                              pooled_part[(size_t)(128 + r0 + rr) * 256 + j]);
    float acc[4];
    #pragma unroll
    for (int rr = 0; rr < 4; ++rr) acc[rr] = smfcb[j];
    for (int ph = 0; ph < 8; ++ph) {
      const float4* src = (const float4*)(smfcW + (size_t)ph * 32 * 256);
      float4* dst = (float4*)wt;
      #pragma unroll
      for (int i = 0; i < 8; ++i) dst[i * 256 + j] = src[i * 256 + j];
      __syncthreads();
      #pragma unroll
      for (int kk = 0; kk < 32; ++kk) {
        float4 x = *reinterpret_cast<const float4*>(&xin[(ph * 32 + kk) * 4]);
        float wv = wt[kk * 256 + j];
        acc[0] += x.x * wv; acc[1] += x.y * wv; acc[2] += x.z * wv; acc[3] += x.w * wv;
      }
      __syncthreads();
    }
    #pragma unroll
    for (int rr = 0; rr < 4; ++rr) {
      int row = r0 + rr;
      feat_comb[(size_t)(row & 63) * 768 + ((row >> 6) * 256) + j] = acc[rr];
    }
  } else {
    float* xin  = lds;           // [256][8]
    float* wt   = lds + 2048;    // [16][512]
    float* sred = lds + 10240;   // [8][4]
    int r0 = (bid - 32) * 8;
    #pragma unroll
    for (int rr = 0; rr < 8; ++rr)
      xin[j * 8 + rr] = fmaxf(pctx_part[(size_t)(r0 + rr) * 256 + j],
                              pctx_part[(size_t)(2560 + r0 + rr) * 256 + j]);
    float hf[8], hh[8];
    float bf0 = bvec[j], bh0 = bvec[256 + j];
    #pragma unroll
    for (int rr = 0; rr < 8; ++rr) {
      hf[rr] = bf0;
      hh[rr] = bh0 + ZQ[(size_t)(r0 + rr) * NQ + 768 + j];
    }
    for (int ph = 0; ph < 16; ++ph) {
      const float4* src = (const float4*)(Wcat + (size_t)ph * 16 * 512);
      float4* dst = (float4*)wt;
      #pragma unroll
      for (int i = 0; i < 8; ++i) dst[i * 256 + j] = src[i * 256 + j];
      __syncthreads();
      #pragma unroll
      for (int kk = 0; kk < 16; ++kk) {
        int k = ph * 16 + kk;
        float4 x0 = *reinterpret_cast<const float4*>(&xin[k * 8]);
        float4 x1 = *reinterpret_cast<const float4*>(&xin[k * 8 + 4]);
        float w0 = wt[kk * 512 + j], w1 = wt[kk * 512 + 256 + j];
        hf[0] += x0.x * w0; hf[1] += x0.y * w0; hf[2] += x0.z * w0; hf[3] += x0.w * w0;
        hf[4] += x1.x * w0; hf[5] += x1.y * w0; hf[6] += x1.z * w0; hf[7] += x1.w * w0;
        hh[0] += x0.x * w1; hh[1] += x0.y * w1; hh[2] += x0.z * w1; hh[3] += x0.w * w1;
        hh[4] += x1.x * w1; hh[5] += x1.y * w1; hh[6] += x1.z * w1; hh[7] += x1.w * w1;
      }
      __syncthreads();
    }
    #pragma unroll
    for (int rr = 0; rr < 8; ++rr)
      feat[(size_t)(r0 + rr) * 256 + j] = hf[rr];
    float pw = probW[j];
    int lane = j & 63, wv = j >> 6;
    #pragma unroll
    for (int rr = 0; rr < 8; ++rr) {
      float s = tanhf(hh[rr]) * pw;
      #pragma unroll
      for (int off = 32; off; off >>= 1) s += __shfl_down(s, off, 64);
      if (lane == 0) sred[rr * 4 + wv] = s;
    }
    __syncthreads();
    if (j < 8) score[r0 + j] = sred[j * 4] + sred[j * 4 + 1] + sred[j * 4 + 2] + sred[j * 4 + 3];
  }
}

// ============ softmax over q + weighted feat pool -> feat_comb[:,512:768] ============
__global__ void k_attnpool(const float* __restrict__ score, const float* __restrict__ feat,
                           float* __restrict__ feat_comb) {
  int b = blockIdx.x;
  int tid = threadIdx.x;
  __shared__ float p[QLn];
  __shared__ float inv;
  if (tid < 64) {
    float sc = (tid < QLn) ? score[b * QLn + tid] : -1e30f;
    float mx = sc;
    #pragma unroll
    for (int off = 32; off; off >>= 1) mx = fmaxf(mx, __shfl_xor(mx, off, 64));
    float e = (tid < QLn) ? expf(sc - mx) : 0.f;
    if (tid < QLn) p[tid] = e;
    float den = e;
    #pragma unroll
    for (int off = 32; off; off >>= 1) den += __shfl_xor(den, off, 64);
    if (tid == 0) inv = 1.f / den;
  }
  __syncthreads();
  float acc = 0.f;
  for (int qq = 0; qq < QLn; ++qq)
    acc += p[qq] * feat[((size_t)b * QLn + qq) * 256 + tid];
  feat_comb[(size_t)b * 768 + 512 + tid] = acc * inv;
}

// ============ fused W1 + bias + BatchNorm + tanh ============
__global__ __launch_bounds__(256) void k_w1bn(
    const float* __restrict__ feat_comb, const float* __restrict__ W1,
    const float* __restrict__ b1, const float* __restrict__ gamma,
    const float* __restrict__ beta, float* __restrict__ feat_out) {
  int j0 = blockIdx.x * 8;
  int tid = threadIdx.x;
  __shared__ float wl[768][12];
  __shared__ float hb[64][8];
  for (int it = 0; it < 24; ++it) {
    int idx = tid + it * 256;
    int k = idx >> 3, jj = idx & 7;
    wl[k][jj] = W1[(size_t)k * 512 + j0 + jj];
  }
  __syncthreads();
  int n = tid >> 2, p = tid & 3;
  float acc[8] = {0.f, 0.f, 0.f, 0.f, 0.f, 0.f, 0.f, 0.f};
  const float* frow = feat_comb + (size_t)n * 768 + p;
  for (int i = 0; i < 192; ++i) {
    float v = frow[i * 4];
    int k = p + i * 4;
    float4 w0 = *reinterpret_cast<const float4*>(&wl[k][0]);
    float4 w1v = *reinterpret_cast<const float4*>(&wl[k][4]);
    acc[0] += v * w0.x; acc[1] += v * w0.y; acc[2] += v * w0.z; acc[3] += v * w0.w;
    acc[4] += v * w1v.x; acc[5] += v * w1v.y; acc[6] += v * w1v.z; acc[7] += v * w1v.w;
  }
  #pragma unroll
  for (int jj = 0; jj < 8; ++jj) {
    acc[jj] += __shfl_xor(acc[jj], 1, 64);
    acc[jj] += __shfl_xor(acc[jj], 2, 64);
  }
  if (p == 0) {
    #pragma unroll
    for (int jj = 0; jj < 8; ++jj) hb[n][jj] = acc[jj] + b1[j0 + jj];
  }
  __syncthreads();
  if (tid < 64) {
    #pragma unroll
    for (int jj = 0; jj < 8; ++jj) {
      float v = hb[tid][jj];
      float s = v;
      #pragma unroll
      for (int off = 32; off; off >>= 1) s += __shfl_xor(s, off, 64);
      float mu = s * (1.f / 64.f);
      float d = v - mu;
      float q2 = d * d;
      #pragma unroll
      for (int off = 32; off; off >>= 1) q2 += __shfl_xor(q2, off, 64);
      float var = q2 * (1.f / 64.f);
      feat_out[(size_t)tid * 512 + j0 + jj] =
          tanhf(d * rsqrtf(var + 1e-5f) * gamma[j0 + jj] + beta[j0 + jj]);
    }
  }
}

// ============ head: 2-class logits + log_softmax ============
__global__ void k_head(const float* __restrict__ feat_out, const float* __restrict__ W2,
                       const float* __restrict__ b2, float* __restrict__ preds) {
  int n = blockIdx.x;
  int tid = threadIdx.x;
  float a0 = 0.f, a1 = 0.f;
  for (int j = tid; j < 512; j += 64) {
    float f = feat_out[(size_t)n * 512 + j];
    a0 += f * W2[j * 2 + 0];
    a1 += f * W2[j * 2 + 1];
  }
  #pragma unroll
  for (int off = 32; off; off >>= 1) {
    a0 += __shfl_down(a0, off, 64);
    a1 += __shfl_down(a1, off, 64);
  }
  if (tid == 0) {
    float l0 = a0 + b2[0], l1 = a1 + b2[1];
    float mx = fmaxf(l0, l1);
    float lse = mx + logf(expf(l0 - mx) + expf(l1 - mx));
    preds[n * 2 + 0] = l0 - lse;
    preds[n * 2 + 1] = l1 - lse;
  }
}

extern "C" void kernel_launch(void* const* d_in, const int* in_sizes, int n_in,
                              void* d_out, int out_size, void* d_ws, size_t ws_size,
                              hipStream_t stream) {
  (void)in_sizes; (void)n_in; (void)out_size; (void)ws_size;
  const int*   question  = (const int*)d_in[0];
  const int*   answer    = (const int*)d_in[1];
  const float* embedding = (const float*)d_in[3];
  const float* sm_convW  = (const float*)d_in[4];
  const float* sm_convb  = (const float*)d_in[5];
  const float* sm_fcW    = (const float*)d_in[6];
  const float* sm_fcb    = (const float*)d_in[7];
  const float* ctx_convW = (const float*)d_in[8];
  const float* ctx_convb = (const float*)d_in[9];
  const float* ctx_fcW   = (const float*)d_in[10];
  const float* ctx_fcb   = (const float*)d_in[11];
  const float* attnW     = (const float*)d_in[12];
  const float* attnb     = (const float*)d_in[13];
  const float* probW     = (const float*)d_in[14];
  const float* W1        = (const float*)d_in[15];
  const float* b1        = (const float*)d_in[16];
  const float* gamma     = (const float*)d_in[17];
  const float* beta      = (const float*)d_in[18];
  const float* W2        = (const float*)d_in[19];
  const float* b2        = (const float*)d_in[20];

  float* out = (float*)d_out;   // [0:128) preds, [128:) feat_out 64x512
  char* base = (char*)d_ws;
  size_t off = 0;
  auto alloc = [&](size_t bytes) { char* p = base + off; off += (bytes + 255) & ~(size_t)255; return p; };

  short* Ae1   = (short*)alloc(2560ull * KS * 2);      // 3.28 MB
  short* Ae2   = (short*)alloc(3840ull * KS * 2);      // 4.92 MB (contiguous after Ae1)
  short* BTall = (short*)alloc(2560ull * KS * 2);      // 3.28 MB; dead after k_mega
  float* ZQ    = (float*)alloc(2560ull * NQ * 4);      // 10.5 MB
  float* ZA    = (float*)alloc(3840ull * NA * 4);      // 23.6 MB
  float* nq    = (float*)alloc(2560 * 4);
  float* na    = (float*)alloc(3840 * 4);
  float* cosb  = (float*)alloc(2560ull * ALn * 4);     // written by k_mega cos job
  float* Wcat  = (float*)alloc(256ull * 512 * 4);
  float* bvec  = (float*)alloc(512 * 4);
  float* pctx_part = (float*)alloc(2ull * 2560 * 256 * 4);
  float* feat      = (float*)alloc(2560ull * 256 * 4);
  float* feat_comb = (float*)alloc(64ull * 768 * 4);
  float* score     = (float*)alloc(2560 * 4);
  float* pooled_part = (float*)BTall;                  // overlay (dead after k_mega)

  // 1. prep: gather+norms | BT-transpose | Wcat (2057 blocks)
  k_prep<<<2057, 256, 0, stream>>>(question, answer, embedding, sm_convW, ctx_convW,
                                   attnW, ctx_fcW, ctx_fcb, attnb,
                                   Ae1, Ae2, nq, na, BTall, Wcat, bvec);
  // 2. split mega GEMM + MFMA cosine (584 blocks)
  k_mega<<<584, 256, 0, stream>>>(Ae1, Ae2, BTall, ZQ, ZA, nq, na, cosb);
  // 3. sm pool | ctx pool (768 blocks)
  k_poolctx<<<768, 256, 0, stream>>>(ZQ, ZA, sm_convb, cosb, ctx_convb,
                                     pooled_part, pctx_part);
  // 4. fc | ctx-fc+attn+score (352 blocks)
  k_fcattn<<<352, 256, 0, stream>>>(pooled_part, sm_fcW, sm_fcb,
                                    pctx_part, Wcat, bvec, ZQ, probW,
                                    feat_comb, feat, score);
  // 5. softmax-pool -> feat_comb cols 512..767
  k_attnpool<<<Bn, 256, 0, stream>>>(score, feat, feat_comb);
  // 6. fused W1 + BN + tanh -> feat_out
  k_w1bn<<<64, 256, 0, stream>>>(feat_comb, W1, b1, gamma, beta, out + 128);
  // 7. head -> preds
  k_head<<<Bn, 64, 0, stream>>>(out + 128, W2, b2, out);
}